// Round 6
// baseline (2248.992 us; speedup 1.0000x reference)
//
#include <hip/hip_runtime.h>
#include <float.h>

#define NEG 0.2f
constexpr int BATCH = 8;
constexpr int NPTS  = 2048;
constexpr int KNN   = 10;
constexpr int KP1   = 11;

__device__ __forceinline__ float lrelu(float x) { return x > 0.f ? x : NEG * x; }

// ---------------- squared-norm per point ----------------
template<int D>
__global__ void sq_kernel(const float* __restrict__ xt, float* __restrict__ sq) {
    int i = blockIdx.x * 256 + threadIdx.x;
    if (i >= BATCH * NPTS) return;
    const float* p = xt + (size_t)i * D;
    float s = 0.f;
    #pragma unroll
    for (int d = 0; d < D; ++d) s += p[d] * p[d];
    sq[i] = s;
}

__global__ void sq64_kernel(const float* __restrict__ xt, float* __restrict__ sq) {
    int i = blockIdx.x * 256 + threadIdx.x;
    if (i >= BATCH * NPTS) return;
    const float4* p = (const float4*)(xt + (size_t)i * 64);
    float4 s4 = {0.f, 0.f, 0.f, 0.f};
    #pragma unroll
    for (int d = 0; d < 16; ++d) {
        float4 v = p[d];
        s4.x += v.x * v.x; s4.y += v.y * v.y; s4.z += v.z * v.z; s4.w += v.w * v.w;
    }
    sq[i] = (s4.x + s4.y) + (s4.z + s4.w);
}

// ---------------- kNN D=3: one block per (b,n), stable top-(K+1) ----------------
template<int D>
__global__ __launch_bounds__(256) void knn_kernel(const float* __restrict__ xt,
                                                  const float* __restrict__ sq,
                                                  int* __restrict__ idx_out) {
    const int bn = blockIdx.x;
    const int b  = bn / NPTS;
    const int tid = threadIdx.x;

    __shared__ float xq[D];
    for (int i = tid; i < D; i += 256) xq[i] = xt[(size_t)bn * D + i];
    __syncthreads();

    const float sqn = sq[bn];
    const float* xb = xt + (size_t)b * NPTS * D;

    float dl[KP1];
    int   il[KP1];
    #pragma unroll
    for (int j = 0; j < KP1; ++j) { dl[j] = FLT_MAX; il[j] = 0x7fffffff; }

    for (int m = tid; m < NPTS; m += 256) {
        const float* xm = xb + (size_t)m * D;
        float dot = 0.f;
        #pragma unroll
        for (int i = 0; i < D; ++i) dot += xq[i] * xm[i];
        float cd = sqn + sq[b * NPTS + m] - 2.f * dot;
        int   ci = m;
        #pragma unroll
        for (int j = 0; j < KP1; ++j) {
            bool better = (cd < dl[j]) || (cd == dl[j] && ci < il[j]);
            float td = dl[j]; int ti = il[j];
            if (better) { dl[j] = cd; il[j] = ci; cd = td; ci = ti; }
        }
    }

    __shared__ float sd[256 * KP1];
    __shared__ int   si[256 * KP1];
    #pragma unroll
    for (int j = 0; j < KP1; ++j) { sd[tid * KP1 + j] = dl[j]; si[tid * KP1 + j] = il[j]; }
    __syncthreads();

    for (int step = 1; step < 256; step <<= 1) {
        if ((tid & (2 * step - 1)) == 0) {
            float* da = sd + tid * KP1;          int* ia = si + tid * KP1;
            float* db = sd + (tid + step) * KP1; int* ib = si + (tid + step) * KP1;
            float rd[KP1]; int ri[KP1];
            int pa = 0, pb = 0;
            #pragma unroll
            for (int j = 0; j < KP1; ++j) {
                float dav = da[pa], dbv = db[pb];
                int   iav = ia[pa], ibv = ib[pb];
                bool takeA = (dav < dbv) || (dav == dbv && iav <= ibv);
                if (takeA) { rd[j] = dav; ri[j] = iav; ++pa; }
                else       { rd[j] = dbv; ri[j] = ibv; ++pb; }
            }
            #pragma unroll
            for (int j = 0; j < KP1; ++j) { da[j] = rd[j]; ia[j] = ri[j]; }
        }
        __syncthreads();
    }

    if (tid < KNN) idx_out[(size_t)bn * KNN + tid] = si[tid + 1];
}

// ---------------- kNN D=64 v3: 2 queries PER LANE (16 per block) ----------------
// Each candidate f4 LDS read now feeds 8 FMAs (2 queries x 4 dims) -> LDS read
// instructions per dispatch halve vs 1-query/lane. Queries live in 32 f4 regs.
// XOR-swizzled tile layout and per-query accumulation order (a0..a3 by dim%4)
// identical to the verified version. Two merge phases share the same scratch.
__global__ __launch_bounds__(256) void knn64_kernel(const float* __restrict__ xt,
                                                    const float* __restrict__ sq,
                                                    int* __restrict__ idx_out) {
    const int t  = threadIdx.x;
    const int g  = t >> 5;   // query-pair group (0..7)
    const int lc = t & 31;   // candidate lane (0..31)
    const int bn0 = blockIdx.x * 16;
    const int qA = bn0 + 2 * g;
    const int qB = qA + 1;
    const int b  = qA >> 11;           // NPTS = 2048
    const float* xb = xt + (size_t)b * NPTS * 64;

    __shared__ __align__(16) char smem[22528];
    float4 (*tile4)[16] = reinterpret_cast<float4(*)[16]>(smem);   // 8 KB (aliases sd)
    float* sd = reinterpret_cast<float*>(smem);                    // 11264 B
    int*   si = reinterpret_cast<int*>(smem + 11264);              // 11264 B

    float4 xqA[16], xqB[16];
    {
        const float4* pa = (const float4*)(xt + (size_t)qA * 64);
        const float4* pb = (const float4*)(xt + (size_t)qB * 64);
        #pragma unroll
        for (int i = 0; i < 16; ++i) { xqA[i] = pa[i]; xqB[i] = pb[i]; }
    }
    const float sqnA = sq[qA], sqnB = sq[qB];
    const float* sqb_ = sq + b * NPTS;

    float dlA[KP1], dlB[KP1];
    int   ilA[KP1], ilB[KP1];
    #pragma unroll
    for (int j = 0; j < KP1; ++j) {
        dlA[j] = FLT_MAX; ilA[j] = 0x7fffffff;
        dlB[j] = FLT_MAX; ilB[j] = 0x7fffffff;
    }

    const int ci  = t >> 3;   // staging: candidate within tile (0..31)
    const int sub = t & 7;    // staging: 8-dim slice (2 f4 slots)

    for (int t0 = 0; t0 < NPTS; t0 += 32) {
        __syncthreads();   // protect previous tile reads
        {
            const float4* src = (const float4*)(xb + (size_t)(t0 + ci) * 64 + sub * 8);
            float4 u0 = src[0], u1 = src[1];
            tile4[ci][(2 * sub)     ^ (ci & 15)] = u0;
            tile4[ci][(2 * sub + 1) ^ (ci & 15)] = u1;
        }
        __syncthreads();

        const int m = t0 + lc;
        float a0 = 0.f, a1 = 0.f, a2 = 0.f, a3 = 0.f;
        float c0 = 0.f, c1 = 0.f, c2 = 0.f, c3 = 0.f;
        #pragma unroll
        for (int i = 0; i < 16; ++i) {
            float4 v = tile4[lc][i ^ (lc & 15)];
            a0 += xqA[i].x * v.x; a1 += xqA[i].y * v.y;
            a2 += xqA[i].z * v.z; a3 += xqA[i].w * v.w;
            c0 += xqB[i].x * v.x; c1 += xqB[i].y * v.y;
            c2 += xqB[i].z * v.z; c3 += xqB[i].w * v.w;
        }
        const float sqm = sqb_[m];
        {
            float cd = sqnA + sqm - 2.f * ((a0 + a1) + (a2 + a3));
            int cidx = m;
            bool ins = (cd < dlA[KP1 - 1]) || (cd == dlA[KP1 - 1] && cidx < ilA[KP1 - 1]);
            if (ins) {
                #pragma unroll
                for (int j = 0; j < KP1; ++j) {
                    bool better = (cd < dlA[j]) || (cd == dlA[j] && cidx < ilA[j]);
                    float td = dlA[j]; int ti = ilA[j];
                    if (better) { dlA[j] = cd; ilA[j] = cidx; cd = td; cidx = ti; }
                }
            }
        }
        {
            float cd = sqnB + sqm - 2.f * ((c0 + c1) + (c2 + c3));
            int cidx = m;
            bool ins = (cd < dlB[KP1 - 1]) || (cd == dlB[KP1 - 1] && cidx < ilB[KP1 - 1]);
            if (ins) {
                #pragma unroll
                for (int j = 0; j < KP1; ++j) {
                    bool better = (cd < dlB[j]) || (cd == dlB[j] && cidx < ilB[j]);
                    float td = dlB[j]; int ti = ilB[j];
                    if (better) { dlB[j] = cd; ilB[j] = cidx; cd = td; cidx = ti; }
                }
            }
        }
    }

    // ---- merge phase A (query qA) ----
    __syncthreads();   // all tile reads done before aliased sd/si writes
    #pragma unroll
    for (int j = 0; j < KP1; ++j) { sd[t * KP1 + j] = dlA[j]; si[t * KP1 + j] = ilA[j]; }
    __syncthreads();
    for (int step = 1; step < 32; step <<= 1) {
        if ((lc & (2 * step - 1)) == 0) {
            float* da = sd + t * KP1;          int* ia = si + t * KP1;
            float* db = sd + (t + step) * KP1; int* ib = si + (t + step) * KP1;
            float rd[KP1]; int ri[KP1];
            int pa = 0, pb = 0;
            #pragma unroll
            for (int j = 0; j < KP1; ++j) {
                float dav = da[pa], dbv = db[pb];
                int   iav = ia[pa], ibv = ib[pb];
                bool takeA = (dav < dbv) || (dav == dbv && iav <= ibv);
                if (takeA) { rd[j] = dav; ri[j] = iav; ++pa; }
                else       { rd[j] = dbv; ri[j] = ibv; ++pb; }
            }
            #pragma unroll
            for (int j = 0; j < KP1; ++j) { da[j] = rd[j]; ia[j] = ri[j]; }
        }
        __syncthreads();
    }
    if (lc < KNN) idx_out[(size_t)qA * KNN + lc] = si[(g * 32) * KP1 + lc + 1];

    // ---- merge phase B (query qB) ----
    __syncthreads();   // phase-A outputs read before overwrite
    #pragma unroll
    for (int j = 0; j < KP1; ++j) { sd[t * KP1 + j] = dlB[j]; si[t * KP1 + j] = ilB[j]; }
    __syncthreads();
    for (int step = 1; step < 32; step <<= 1) {
        if ((lc & (2 * step - 1)) == 0) {
            float* da = sd + t * KP1;          int* ia = si + t * KP1;
            float* db = sd + (t + step) * KP1; int* ib = si + (t + step) * KP1;
            float rd[KP1]; int ri[KP1];
            int pa = 0, pb = 0;
            #pragma unroll
            for (int j = 0; j < KP1; ++j) {
                float dav = da[pa], dbv = db[pb];
                int   iav = ia[pa], ibv = ib[pb];
                bool takeA = (dav < dbv) || (dav == dbv && iav <= ibv);
                if (takeA) { rd[j] = dav; ri[j] = iav; ++pa; }
                else       { rd[j] = dbv; ri[j] = ibv; ++pb; }
            }
            #pragma unroll
            for (int j = 0; j < KP1; ++j) { da[j] = rd[j]; ia[j] = ri[j]; }
        }
        __syncthreads();
    }
    if (lc < KNN) idx_out[(size_t)qB * KNN + lc] = si[(g * 32) * KP1 + lc + 1];
}

// ---------------- edge conv stage 1: points(3) -> 64 -> 64 -> max_k ----------------
__global__ __launch_bounds__(64) void edgeconv1_kernel(
    const float* __restrict__ pts, const int* __restrict__ idx,
    const float* __restrict__ w1, const float* __restrict__ s1, const float* __restrict__ b1,
    const float* __restrict__ w2, const float* __restrict__ s2, const float* __restrict__ b2,
    float* __restrict__ outt) {
    const int bn = blockIdx.x;
    const int b  = bn / NPTS;
    const int c  = threadIdx.x;

    const float cx = pts[bn * 3 + 0], cy = pts[bn * 3 + 1], cz = pts[bn * 3 + 2];

    float w1r[6];
    #pragma unroll
    for (int i = 0; i < 6; ++i) w1r[i] = w1[c * 6 + i];
    const float s1c = s1[c], b1c = b1[c], s2c = s2[c], b2c = b2[c];

    __shared__ float h1all[KNN][64];
    #pragma unroll
    for (int k = 0; k < KNN; ++k) {
        const int m = idx[bn * KNN + k];
        const float* f = pts + ((size_t)b * NPTS + m) * 3;
        const float e0 = f[0] - cx, e1 = f[1] - cy, e2 = f[2] - cz;
        float a = w1r[0] * e0 + w1r[1] * e1 + w1r[2] * e2
                + w1r[3] * cx + w1r[4] * cy + w1r[5] * cz;
        h1all[k][c] = lrelu(a * s1c + b1c);
    }
    __syncthreads();

    float a2[KNN];
    #pragma unroll
    for (int k = 0; k < KNN; ++k) a2[k] = 0.f;
    for (int j4 = 0; j4 < 16; ++j4) {
        float4 wv = *(const float4*)&w2[c * 64 + j4 * 4];
        #pragma unroll
        for (int k = 0; k < KNN; ++k) {
            float4 h4 = *(const float4*)&h1all[k][j4 * 4];
            a2[k] += wv.x * h4.x + wv.y * h4.y + wv.z * h4.z + wv.w * h4.w;
        }
    }
    float mx = -FLT_MAX;
    #pragma unroll
    for (int k = 0; k < KNN; ++k) mx = fmaxf(mx, lrelu(a2[k] * s2c + b2c));
    outt[(size_t)bn * 64 + c] = mx;
}

// ---------------- edge conv stage 2: feat64 -> (128) -> 64 -> 64 -> max_k ----------------
__global__ __launch_bounds__(64) void edgeconv2_kernel(
    const float* __restrict__ xin, const int* __restrict__ idx,
    const float* __restrict__ w3, const float* __restrict__ s3, const float* __restrict__ b3,
    const float* __restrict__ w4, const float* __restrict__ s4, const float* __restrict__ b4,
    float* __restrict__ outt) {
    const int bn = blockIdx.x;
    const int b  = bn / NPTS;
    const int c  = threadIdx.x;

    __shared__ float cen[64];
    __shared__ float fea[KNN][64];
    __shared__ float h1all[KNN][64];
    cen[c] = xin[(size_t)bn * 64 + c];
    #pragma unroll
    for (int k = 0; k < KNN; ++k) {
        const int m = idx[bn * KNN + k];
        fea[k][c] = xin[((size_t)b * NPTS + m) * 64 + c];
    }
    __syncthreads();

    float a[KNN];
    #pragma unroll
    for (int k = 0; k < KNN; ++k) a[k] = 0.f;
    float4 ab = {0.f, 0.f, 0.f, 0.f};
    for (int j4 = 0; j4 < 16; ++j4) {
        float4 wa = *(const float4*)&w3[c * 128 + j4 * 4];
        float4 wb = *(const float4*)&w3[c * 128 + 64 + j4 * 4];
        float4 c4 = *(const float4*)&cen[j4 * 4];
        ab.x += (wb.x - wa.x) * c4.x; ab.y += (wb.y - wa.y) * c4.y;
        ab.z += (wb.z - wa.z) * c4.z; ab.w += (wb.w - wa.w) * c4.w;
        #pragma unroll
        for (int k = 0; k < KNN; ++k) {
            float4 f4 = *(const float4*)&fea[k][j4 * 4];
            a[k] += wa.x * f4.x + wa.y * f4.y + wa.z * f4.z + wa.w * f4.w;
        }
    }
    const float abase = (ab.x + ab.y) + (ab.z + ab.w);
    const float s3c = s3[c], b3c = b3[c], s4c = s4[c], b4c = b4[c];
    #pragma unroll
    for (int k = 0; k < KNN; ++k) h1all[k][c] = lrelu((a[k] + abase) * s3c + b3c);
    __syncthreads();

    float a2[KNN];
    #pragma unroll
    for (int k = 0; k < KNN; ++k) a2[k] = 0.f;
    for (int j4 = 0; j4 < 16; ++j4) {
        float4 wv = *(const float4*)&w4[c * 64 + j4 * 4];
        #pragma unroll
        for (int k = 0; k < KNN; ++k) {
            float4 h4 = *(const float4*)&h1all[k][j4 * 4];
            a2[k] += wv.x * h4.x + wv.y * h4.y + wv.z * h4.z + wv.w * h4.w;
        }
    }
    float mx = -FLT_MAX;
    #pragma unroll
    for (int k = 0; k < KNN; ++k) mx = fmaxf(mx, lrelu(a2[k] * s4c + b4c));
    outt[(size_t)bn * 64 + c] = mx;
}

// ---------------- edge conv stage 3: feat64 -> (128) -> 64 -> max_k ----------------
__global__ __launch_bounds__(64) void edgeconv3_kernel(
    const float* __restrict__ xin, const int* __restrict__ idx,
    const float* __restrict__ w5, const float* __restrict__ s5, const float* __restrict__ b5,
    float* __restrict__ outt) {
    const int bn = blockIdx.x;
    const int b  = bn / NPTS;
    const int c  = threadIdx.x;

    __shared__ float cen[64];
    __shared__ float fea[KNN][64];
    cen[c] = xin[(size_t)bn * 64 + c];
    #pragma unroll
    for (int k = 0; k < KNN; ++k) {
        const int m = idx[bn * KNN + k];
        fea[k][c] = xin[((size_t)b * NPTS + m) * 64 + c];
    }
    __syncthreads();

    float a[KNN];
    #pragma unroll
    for (int k = 0; k < KNN; ++k) a[k] = 0.f;
    float4 ab = {0.f, 0.f, 0.f, 0.f};
    for (int j4 = 0; j4 < 16; ++j4) {
        float4 wa = *(const float4*)&w5[c * 128 + j4 * 4];
        float4 wb = *(const float4*)&w5[c * 128 + 64 + j4 * 4];
        float4 c4 = *(const float4*)&cen[j4 * 4];
        ab.x += (wb.x - wa.x) * c4.x; ab.y += (wb.y - wa.y) * c4.y;
        ab.z += (wb.z - wa.z) * c4.z; ab.w += (wb.w - wa.w) * c4.w;
        #pragma unroll
        for (int k = 0; k < KNN; ++k) {
            float4 f4 = *(const float4*)&fea[k][j4 * 4];
            a[k] += wa.x * f4.x + wa.y * f4.y + wa.z * f4.z + wa.w * f4.w;
        }
    }
    const float abase = (ab.x + ab.y) + (ab.z + ab.w);
    const float s5c = s5[c], b5c = b5[c];
    float mx = -FLT_MAX;
    #pragma unroll
    for (int k = 0; k < KNN; ++k) mx = fmaxf(mx, lrelu((a[k] + abase) * s5c + b5c));
    outt[(size_t)bn * 64 + c] = mx;
}

// ---------------- label branch: (16) -> 64 ----------------
__global__ __launch_bounds__(64) void catvet_kernel(
    const float* __restrict__ label,
    const float* __restrict__ w7, const float* __restrict__ s7, const float* __restrict__ b7,
    float* __restrict__ catv) {
    const int b = blockIdx.x, c = threadIdx.x;
    float a = 0.f;
    #pragma unroll
    for (int i = 0; i < 16; ++i) a += w7[c * 16 + i] * label[b * 16 + i];
    catv[b * 64 + c] = lrelu(a * s7[c] + b7[c]);
}

// ---------------- w6 transpose: w6t[k][c] = w6[c][k] (one-time, 768 KB) ----------------
__global__ void w6t_kernel(const float* __restrict__ w6, float* __restrict__ w6t) {
    int i = blockIdx.x * 256 + threadIdx.x;
    if (i >= 192 * 1024) return;
    int k = i >> 10, c = i & 1023;
    w6t[i] = w6[c * 192 + k];
}

// ---------------- global feature GEMM: raw max_n( w6 . x[n] ) per channel ----------------
constexpr int OPTS = 32;
__global__ __launch_bounds__(256) void out4max_kernel(
    const float* __restrict__ out1t, const float* __restrict__ out2t, const float* __restrict__ out3t,
    const float* __restrict__ w6t, float* __restrict__ partial) {
    const int blk = blockIdx.x;
    const int b   = blk >> 6;
    const int nt  = blk & 63;
    const int t   = threadIdx.x;

    __shared__ float xs[192 * OPTS];   // [k][p], 24 KB; reads are all-lane broadcasts
    for (int idx = t; idx < 192 * OPTS; idx += 256) {
        int p = idx / 192, r = idx - p * 192;
        const size_t gp = (size_t)b * NPTS + nt * OPTS + p;
        float val;
        if (r < 64)       val = out1t[gp * 64 + r];
        else if (r < 128) val = out2t[gp * 64 + (r - 64)];
        else              val = out3t[gp * 64 + (r - 128)];
        xs[r * OPTS + p] = val;
    }
    __syncthreads();

    float mx0 = -FLT_MAX, mx1 = -FLT_MAX, mx2 = -FLT_MAX, mx3 = -FLT_MAX;
    #pragma unroll
    for (int pg = 0; pg < OPTS / 16; ++pg) {
        float acc0[16], acc1[16], acc2[16], acc3[16];
        #pragma unroll
        for (int p = 0; p < 16; ++p) { acc0[p] = 0.f; acc1[p] = 0.f; acc2[p] = 0.f; acc3[p] = 0.f; }
        #pragma unroll 2
        for (int k = 0; k < 192; ++k) {
            float4 wv = *(const float4*)&w6t[(size_t)k * 1024 + t * 4];
            const float4* xr4 = (const float4*)&xs[k * OPTS + pg * 16];
            #pragma unroll
            for (int p4 = 0; p4 < 4; ++p4) {
                float4 xv = xr4[p4];
                acc0[p4 * 4 + 0] += wv.x * xv.x; acc0[p4 * 4 + 1] += wv.x * xv.y;
                acc0[p4 * 4 + 2] += wv.x * xv.z; acc0[p4 * 4 + 3] += wv.x * xv.w;
                acc1[p4 * 4 + 0] += wv.y * xv.x; acc1[p4 * 4 + 1] += wv.y * xv.y;
                acc1[p4 * 4 + 2] += wv.y * xv.z; acc1[p4 * 4 + 3] += wv.y * xv.w;
                acc2[p4 * 4 + 0] += wv.z * xv.x; acc2[p4 * 4 + 1] += wv.z * xv.y;
                acc2[p4 * 4 + 2] += wv.z * xv.z; acc2[p4 * 4 + 3] += wv.z * xv.w;
                acc3[p4 * 4 + 0] += wv.w * xv.x; acc3[p4 * 4 + 1] += wv.w * xv.y;
                acc3[p4 * 4 + 2] += wv.w * xv.z; acc3[p4 * 4 + 3] += wv.w * xv.w;
            }
        }
        #pragma unroll
        for (int p = 0; p < 16; ++p) {
            mx0 = fmaxf(mx0, acc0[p]); mx1 = fmaxf(mx1, acc1[p]);
            mx2 = fmaxf(mx2, acc2[p]); mx3 = fmaxf(mx3, acc3[p]);
        }
    }
    float4 o = {mx0, mx1, mx2, mx3};
    *(float4*)&partial[(size_t)blk * 1024 + t * 4] = o;
}

__global__ __launch_bounds__(256) void out4reduce_kernel(
    const float* __restrict__ partial,
    const float* __restrict__ s6, const float* __restrict__ b6,
    float* __restrict__ out4m) {
    const int i = blockIdx.x * 256 + threadIdx.x;  // 8192 = 8 * 1024
    const int b = i >> 10, c = i & 1023;
    float m = -FLT_MAX;
    for (int nt = 0; nt < 64; ++nt)
        m = fmaxf(m, partial[((size_t)b * 64 + nt) * 1024 + c]);
    out4m[i] = lrelu(m * s6[c] + b6[c]);
}

// ---------------- per-batch head bias: g[b][o] = wp1[o,192:1280] . [out4m;catv] ----------------
__global__ __launch_bounds__(256) void gbias_kernel(
    const float* __restrict__ out4m, const float* __restrict__ catv,
    const float* __restrict__ wp1, float* __restrict__ g) {
    const int b = blockIdx.x, t = threadIdx.x;
    __shared__ float v[1088];
    for (int i = t; i < 1088; i += 256)
        v[i] = (i < 1024) ? out4m[(size_t)b * 1024 + i] : catv[(size_t)b * 64 + (i - 1024)];
    __syncthreads();
    const float* w = wp1 + (size_t)t * 1280 + 192;
    float4 s4 = {0.f, 0.f, 0.f, 0.f};
    for (int i = 0; i < 272; ++i) {
        float4 wv = *(const float4*)&w[i * 4];
        float4 vv = *(const float4*)&v[i * 4];
        s4.x += wv.x * vv.x; s4.y += wv.y * vv.y; s4.z += wv.z * vv.z; s4.w += wv.w * vv.w;
    }
    g[(size_t)b * 256 + t] = (s4.x + s4.y) + (s4.z + s4.w);
}

// ---------------- per-point head (tiled GEMM): 192 -> 256 -> 256 -> 128 -> 6 ----------------
constexpr int HP = 16;   // points per block
constexpr int KC = 16;   // k-chunk

__global__ __launch_bounds__(256) void head_kernel(
    const float* __restrict__ out1t, const float* __restrict__ out2t, const float* __restrict__ out3t,
    const float* __restrict__ g,
    const float* __restrict__ wp1, const float* __restrict__ sp1, const float* __restrict__ bp1,
    const float* __restrict__ wp2, const float* __restrict__ sp2, const float* __restrict__ bp2,
    const float* __restrict__ wp3, const float* __restrict__ sp3, const float* __restrict__ bp3,
    const float* __restrict__ wp4, float* __restrict__ out) {
    const int p0 = blockIdx.x * HP;
    const int b  = p0 >> 11;
    const int t  = threadIdx.x;

    __shared__ float smA[4096];      // xs[192][16] then t2s[256][16]
    __shared__ float smB[4096];      // t1s[256][16] then t3s[128][16]
    __shared__ float smW[KC * 256];  // weight chunk, k-major

    for (int e = t; e < 192 * HP; e += 256) {
        int p = e / 192, k = e - p * 192;
        float val;
        if (k < 64)       val = out1t[((size_t)(p0 + p)) * 64 + k];
        else if (k < 128) val = out2t[((size_t)(p0 + p)) * 64 + (k - 64)];
        else              val = out3t[((size_t)(p0 + p)) * 64 + (k - 128)];
        smA[k * HP + p] = val;
    }

    const int og = t & 31;   // 8 outs each
    const int pg = t >> 5;   // 2 points each

    // ---- layer 1: 192 -> 256, acc init = per-batch g ----
    float acc[2][8];
    #pragma unroll
    for (int i = 0; i < 8; ++i) {
        float gv = g[(size_t)b * 256 + og * 8 + i];
        acc[0][i] = gv; acc[1][i] = gv;
    }
    for (int kc = 0; kc < 192 / KC; ++kc) {
        __syncthreads();
        #pragma unroll
        for (int it = 0; it < KC; ++it)
            smW[it * 256 + t] = wp1[(size_t)t * 1280 + kc * KC + it];
        __syncthreads();
        #pragma unroll 4
        for (int kk = 0; kk < KC; ++kk) {
            int k = kc * KC + kk;
            float2 xv = *(const float2*)&smA[k * HP + pg * 2];
            float4 w0 = *(const float4*)&smW[kk * 256 + og * 8];
            float4 w1v = *(const float4*)&smW[kk * 256 + og * 8 + 4];
            float wv[8] = {w0.x, w0.y, w0.z, w0.w, w1v.x, w1v.y, w1v.z, w1v.w};
            #pragma unroll
            for (int i = 0; i < 8; ++i) {
                acc[0][i] += xv.x * wv[i];
                acc[1][i] += xv.y * wv[i];
            }
        }
    }
    #pragma unroll
    for (int i = 0; i < 8; ++i) {
        int o = og * 8 + i;
        float sc = sp1[o], bc = bp1[o];
        smB[o * HP + pg * 2 + 0] = lrelu(acc[0][i] * sc + bc);
        smB[o * HP + pg * 2 + 1] = lrelu(acc[1][i] * sc + bc);
    }

    // ---- layer 2: 256 -> 256 ----
    float acc2[2][8];
    #pragma unroll
    for (int i = 0; i < 8; ++i) { acc2[0][i] = 0.f; acc2[1][i] = 0.f; }
    for (int kc = 0; kc < 256 / KC; ++kc) {
        __syncthreads();
        #pragma unroll
        for (int it = 0; it < KC; ++it)
            smW[it * 256 + t] = wp2[(size_t)t * 256 + kc * KC + it];
        __syncthreads();
        #pragma unroll 4
        for (int kk = 0; kk < KC; ++kk) {
            int k = kc * KC + kk;
            float2 xv = *(const float2*)&smB[k * HP + pg * 2];
            float4 w0 = *(const float4*)&smW[kk * 256 + og * 8];
            float4 w1v = *(const float4*)&smW[kk * 256 + og * 8 + 4];
            float wv[8] = {w0.x, w0.y, w0.z, w0.w, w1v.x, w1v.y, w1v.z, w1v.w};
            #pragma unroll
            for (int i = 0; i < 8; ++i) {
                acc2[0][i] += xv.x * wv[i];
                acc2[1][i] += xv.y * wv[i];
            }
        }
    }
    __syncthreads();
    #pragma unroll
    for (int i = 0; i < 8; ++i) {
        int o = og * 8 + i;
        float sc = sp2[o], bc = bp2[o];
        smA[o * HP + pg * 2 + 0] = lrelu(acc2[0][i] * sc + bc);
        smA[o * HP + pg * 2 + 1] = lrelu(acc2[1][i] * sc + bc);
    }

    // ---- layer 3: 256 -> 128 ----
    const int og3 = t & 15;
    const int p3  = t >> 4;
    float acc3[8];
    #pragma unroll
    for (int i = 0; i < 8; ++i) acc3[i] = 0.f;
    for (int kc = 0; kc < 256 / KC; ++kc) {
        __syncthreads();
        for (int e = t; e < KC * 128; e += 256) {
            int kk = e >> 7, o = e & 127;
            smW[kk * 128 + o] = wp3[(size_t)o * 256 + kc * KC + kk];
        }
        __syncthreads();
        #pragma unroll 4
        for (int kk = 0; kk < KC; ++kk) {
            int k = kc * KC + kk;
            float xv = smA[k * HP + p3];
            float4 w0 = *(const float4*)&smW[kk * 128 + og3 * 8];
            float4 w1v = *(const float4*)&smW[kk * 128 + og3 * 8 + 4];
            float wv[8] = {w0.x, w0.y, w0.z, w0.w, w1v.x, w1v.y, w1v.z, w1v.w};
            #pragma unroll
            for (int i = 0; i < 8; ++i) acc3[i] += xv * wv[i];
        }
    }
    __syncthreads();
    #pragma unroll
    for (int i = 0; i < 8; ++i) {
        int o = og3 * 8 + i;
        float sc = sp3[o], bc = bp3[o];
        smB[o * HP + p3] = lrelu(acc3[i] * sc + bc);
    }
    __syncthreads();

    // ---- layer 4: 128 -> 6 ----
    if (t < HP * 6) {
        int p = t / 6, o = t - p * 6;
        float4 s4 = {0.f, 0.f, 0.f, 0.f};
        for (int k4 = 0; k4 < 32; ++k4) {
            float4 wv = *(const float4*)&wp4[o * 128 + k4 * 4];
            s4.x += wv.x * smB[(k4 * 4 + 0) * HP + p];
            s4.y += wv.y * smB[(k4 * 4 + 1) * HP + p];
            s4.z += wv.z * smB[(k4 * 4 + 2) * HP + p];
            s4.w += wv.w * smB[(k4 * 4 + 3) * HP + p];
        }
        out[((size_t)(p0 + p)) * 6 + o] = (s4.x + s4.y) + (s4.z + s4.w);
    }
}

extern "C" void kernel_launch(void* const* d_in, const int* in_sizes, int n_in,
                              void* d_out, int out_size, void* d_ws, size_t ws_size,
                              hipStream_t stream) {
    const float* points = (const float*)d_in[0];
    const float* label  = (const float*)d_in[1];
    const float* w1  = (const float*)d_in[2];
    const float* s1  = (const float*)d_in[3];
    const float* b1  = (const float*)d_in[4];
    const float* w2  = (const float*)d_in[5];
    const float* s2  = (const float*)d_in[6];
    const float* b2  = (const float*)d_in[7];
    const float* w3  = (const float*)d_in[8];
    const float* s3  = (const float*)d_in[9];
    const float* b3  = (const float*)d_in[10];
    const float* w4  = (const float*)d_in[11];
    const float* s4  = (const float*)d_in[12];
    const float* b4  = (const float*)d_in[13];
    const float* w5  = (const float*)d_in[14];
    const float* s5  = (const float*)d_in[15];
    const float* b5  = (const float*)d_in[16];
    const float* w6  = (const float*)d_in[17];
    const float* s6  = (const float*)d_in[18];
    const float* b6  = (const float*)d_in[19];
    const float* w7  = (const float*)d_in[20];
    const float* s7  = (const float*)d_in[21];
    const float* b7  = (const float*)d_in[22];
    const float* wp1 = (const float*)d_in[23];
    const float* sp1 = (const float*)d_in[24];
    const float* bp1 = (const float*)d_in[25];
    const float* wp2 = (const float*)d_in[26];
    const float* sp2 = (const float*)d_in[27];
    const float* bp2 = (const float*)d_in[28];
    const float* wp3 = (const float*)d_in[29];
    const float* sp3 = (const float*)d_in[30];
    const float* bp3 = (const float*)d_in[31];
    const float* wp4 = (const float*)d_in[32];

    float* ws = (float*)d_ws;
    size_t off = 0;
    auto alloc = [&](size_t nf) { float* p = ws + off; off += nf; return p; };
    float* out1t = alloc((size_t)BATCH * NPTS * 64);
    float* out2t = alloc((size_t)BATCH * NPTS * 64);
    float* out3t = alloc((size_t)BATCH * NPTS * 64);
    float* sqb   = alloc((size_t)BATCH * NPTS);
    float* out4m = alloc((size_t)BATCH * 1024);
    float* catv  = alloc((size_t)BATCH * 64);
    float* gb    = alloc((size_t)BATCH * 256);
    float* w6t   = alloc((size_t)192 * 1024);
    float* part  = alloc((size_t)512 * 1024);
    int* idx1 = (int*)alloc((size_t)BATCH * NPTS * KNN);
    int* idx2 = (int*)alloc((size_t)BATCH * NPTS * KNN);
    int* idx3 = (int*)alloc((size_t)BATCH * NPTS * KNN);

    const int BN = BATCH * NPTS;
    const int sqBlocks = (BN + 255) / 256;

    // stage 1
    sq_kernel<3><<<sqBlocks, 256, 0, stream>>>(points, sqb);
    knn_kernel<3><<<BN, 256, 0, stream>>>(points, sqb, idx1);
    edgeconv1_kernel<<<BN, 64, 0, stream>>>(points, idx1, w1, s1, b1, w2, s2, b2, out1t);

    // stage 2
    sq64_kernel<<<sqBlocks, 256, 0, stream>>>(out1t, sqb);
    knn64_kernel<<<BN / 16, 256, 0, stream>>>(out1t, sqb, idx2);
    edgeconv2_kernel<<<BN, 64, 0, stream>>>(out1t, idx2, w3, s3, b3, w4, s4, b4, out2t);

    // stage 3
    sq64_kernel<<<sqBlocks, 256, 0, stream>>>(out2t, sqb);
    knn64_kernel<<<BN / 16, 256, 0, stream>>>(out2t, sqb, idx3);
    edgeconv3_kernel<<<BN, 64, 0, stream>>>(out2t, idx3, w5, s5, b5, out3t);

    // global branches
    catvet_kernel<<<BATCH, 64, 0, stream>>>(label, w7, s7, b7, catv);
    w6t_kernel<<<(192 * 1024 + 255) / 256, 256, 0, stream>>>(w6, w6t);
    out4max_kernel<<<512, 256, 0, stream>>>(out1t, out2t, out3t, w6t, part);
    out4reduce_kernel<<<BATCH * 1024 / 256, 256, 0, stream>>>(part, s6, b6, out4m);
    gbias_kernel<<<BATCH, 256, 0, stream>>>(out4m, catv, wp1, gb);

    // head
    head_kernel<<<BN / HP, 256, 0, stream>>>(out1t, out2t, out3t, gb,
                                             wp1, sp1, bp1, wp2, sp2, bp2, wp3, sp3, bp3,
                                             wp4, (float*)d_out);
}

// Round 7
// 1154.445 us; speedup vs baseline: 1.9481x; 1.9481x over previous
//
#include <hip/hip_runtime.h>
#include <float.h>

#define NEG 0.2f
constexpr int BATCH = 8;
constexpr int NPTS  = 2048;
constexpr int KNN   = 10;
constexpr int KP1   = 11;

__device__ __forceinline__ float lrelu(float x) { return x > 0.f ? x : NEG * x; }

// ordered-u64 key: (monotone uint of d2) << 32 | idx  => u64 '<' == (d2 asc, idx asc)
__device__ __forceinline__ unsigned long long dkey(float d, int m) {
    unsigned u = __float_as_uint(d);
    u ^= (unsigned)((int)u >> 31) | 0x80000000u;
    return ((unsigned long long)u << 32) | (unsigned)m;
}

// ---------------- squared-norm per point ----------------
template<int D>
__global__ void sq_kernel(const float* __restrict__ xt, float* __restrict__ sq) {
    int i = blockIdx.x * 256 + threadIdx.x;
    if (i >= BATCH * NPTS) return;
    const float* p = xt + (size_t)i * D;
    float s = 0.f;
    #pragma unroll
    for (int d = 0; d < D; ++d) s += p[d] * p[d];
    sq[i] = s;
}

__global__ void sq64_kernel(const float* __restrict__ xt, float* __restrict__ sq) {
    int i = blockIdx.x * 256 + threadIdx.x;
    if (i >= BATCH * NPTS) return;
    const float4* p = (const float4*)(xt + (size_t)i * 64);
    float4 s4 = {0.f, 0.f, 0.f, 0.f};
    #pragma unroll
    for (int d = 0; d < 16; ++d) {
        float4 v = p[d];
        s4.x += v.x * v.x; s4.y += v.y * v.y; s4.z += v.z * v.z; s4.w += v.w * v.w;
    }
    sq[i] = (s4.x + s4.y) + (s4.z + s4.w);
}

// ---------------- kNN D=3: one block per (b,n), u64-key top-(K+1) ----------------
template<int D>
__global__ __launch_bounds__(256) void knn_kernel(const float* __restrict__ xt,
                                                  const float* __restrict__ sq,
                                                  int* __restrict__ idx_out) {
    const int bn = blockIdx.x;
    const int b  = bn / NPTS;
    const int tid = threadIdx.x;

    __shared__ float xq[D];
    for (int i = tid; i < D; i += 256) xq[i] = xt[(size_t)bn * D + i];
    __syncthreads();

    const float sqn = sq[bn];
    const float* xb = xt + (size_t)b * NPTS * D;

    unsigned long long lk[KP1];
    #pragma unroll
    for (int j = 0; j < KP1; ++j) lk[j] = ~0ULL;

    for (int m = tid; m < NPTS; m += 256) {
        const float* xm = xb + (size_t)m * D;
        float dot = 0.f;
        #pragma unroll
        for (int i = 0; i < D; ++i) dot += xq[i] * xm[i];
        float cd = sqn + sq[b * NPTS + m] - 2.f * dot;
        unsigned long long key = dkey(cd, m);
        if (key < lk[KP1 - 1]) {
            #pragma unroll
            for (int j = 0; j < KP1; ++j) {
                bool better = key < lk[j];
                unsigned long long tk = lk[j];
                if (better) { lk[j] = key; key = tk; }
            }
        }
    }

    __shared__ unsigned long long sk[256 * KP1];   // 22528 B
    #pragma unroll
    for (int j = 0; j < KP1; ++j) sk[tid * KP1 + j] = lk[j];
    __syncthreads();

    for (int step = 1; step < 256; step <<= 1) {
        if ((tid & (2 * step - 1)) == 0) {
            unsigned long long* ka = sk + tid * KP1;
            unsigned long long* kb = sk + (tid + step) * KP1;
            unsigned long long rk[KP1];
            int pa = 0, pb = 0;
            #pragma unroll
            for (int j = 0; j < KP1; ++j) {
                unsigned long long av = ka[pa], bv = kb[pb];
                bool takeA = av < bv;   // keys unique -> strict order suffices
                if (takeA) { rk[j] = av; ++pa; } else { rk[j] = bv; ++pb; }
            }
            #pragma unroll
            for (int j = 0; j < KP1; ++j) ka[j] = rk[j];
        }
        __syncthreads();
    }

    if (tid < KNN) idx_out[(size_t)bn * KNN + tid] = (int)(unsigned)(sk[tid + 1]);
}

// ---------------- kNN D=64: 8 queries/block (v2 structure) + u64-key selection ----------------
// XOR-swizzled f4 tile; dot accumulation order (a0..a3 by dim%4) identical to verified
// version; u64 key (d2,idx) makes insert 1 cmp + selects per step, exact tie-break.
__global__ __launch_bounds__(256) void knn64_kernel(const float* __restrict__ xt,
                                                    const float* __restrict__ sq,
                                                    int* __restrict__ idx_out) {
    const int t  = threadIdx.x;
    const int qg = t >> 5;   // query within block (0..7)
    const int lc = t & 31;   // candidate lane (0..31)
    const int bn0 = blockIdx.x * 8;
    const int bn  = bn0 + qg;
    const int b   = bn >> 11;          // NPTS = 2048
    const float* xb = xt + (size_t)b * NPTS * 64;

    __shared__ __align__(16) char smem[22528];
    float4 (*tile4)[16] = reinterpret_cast<float4(*)[16]>(smem);                  // 8 KB (aliases sk)
    unsigned long long* sk = reinterpret_cast<unsigned long long*>(smem);         // 256*11*8 = 22528 B

    float4 xq[16];
    {
        const float4* xqp = (const float4*)(xt + (size_t)bn * 64);
        #pragma unroll
        for (int i = 0; i < 16; ++i) xq[i] = xqp[i];
    }
    const float sqn = sq[bn];
    const float* sqb_ = sq + b * NPTS;

    unsigned long long lk[KP1];
    #pragma unroll
    for (int j = 0; j < KP1; ++j) lk[j] = ~0ULL;

    const int ci  = t >> 3;   // staging: candidate within tile (0..31)
    const int sub = t & 7;    // staging: 8-dim slice (2 f4 slots)

    for (int t0 = 0; t0 < NPTS; t0 += 32) {
        __syncthreads();   // protect previous tile reads
        {
            const float4* src = (const float4*)(xb + (size_t)(t0 + ci) * 64 + sub * 8);
            float4 u0 = src[0], u1 = src[1];
            tile4[ci][(2 * sub)     ^ (ci & 15)] = u0;
            tile4[ci][(2 * sub + 1) ^ (ci & 15)] = u1;
        }
        __syncthreads();

        const int m = t0 + lc;
        float a0 = 0.f, a1 = 0.f, a2 = 0.f, a3 = 0.f;
        #pragma unroll
        for (int i = 0; i < 16; ++i) {
            float4 v = tile4[lc][i ^ (lc & 15)];
            a0 += xq[i].x * v.x;
            a1 += xq[i].y * v.y;
            a2 += xq[i].z * v.z;
            a3 += xq[i].w * v.w;
        }
        float dot = (a0 + a1) + (a2 + a3);
        float cd = sqn + sqb_[m] - 2.f * dot;
        unsigned long long key = dkey(cd, m);
        if (key < lk[KP1 - 1]) {
            #pragma unroll
            for (int j = 0; j < KP1; ++j) {
                bool better = key < lk[j];
                unsigned long long tk = lk[j];
                if (better) { lk[j] = key; key = tk; }
            }
        }
    }

    __syncthreads();   // all tile reads done before aliased sk writes
    #pragma unroll
    for (int j = 0; j < KP1; ++j) sk[t * KP1 + j] = lk[j];
    __syncthreads();

    for (int step = 1; step < 32; step <<= 1) {
        if ((lc & (2 * step - 1)) == 0) {
            unsigned long long* ka = sk + t * KP1;
            unsigned long long* kb = sk + (t + step) * KP1;
            unsigned long long rk[KP1];
            int pa = 0, pb = 0;
            #pragma unroll
            for (int j = 0; j < KP1; ++j) {
                unsigned long long av = ka[pa], bv = kb[pb];
                bool takeA = av < bv;
                if (takeA) { rk[j] = av; ++pa; } else { rk[j] = bv; ++pb; }
            }
            #pragma unroll
            for (int j = 0; j < KP1; ++j) ka[j] = rk[j];
        }
        __syncthreads();
    }

    if (lc < KNN) idx_out[(size_t)bn * KNN + lc] = (int)(unsigned)(sk[(qg * 32) * KP1 + lc + 1]);
}

// ---------------- edge conv stage 1: points(3) -> 64 -> 64 -> max_k ----------------
__global__ __launch_bounds__(64) void edgeconv1_kernel(
    const float* __restrict__ pts, const int* __restrict__ idx,
    const float* __restrict__ w1, const float* __restrict__ s1, const float* __restrict__ b1,
    const float* __restrict__ w2, const float* __restrict__ s2, const float* __restrict__ b2,
    float* __restrict__ outt) {
    const int bn = blockIdx.x;
    const int b  = bn / NPTS;
    const int c  = threadIdx.x;

    const float cx = pts[bn * 3 + 0], cy = pts[bn * 3 + 1], cz = pts[bn * 3 + 2];

    float w1r[6];
    #pragma unroll
    for (int i = 0; i < 6; ++i) w1r[i] = w1[c * 6 + i];
    const float s1c = s1[c], b1c = b1[c], s2c = s2[c], b2c = b2[c];

    __shared__ float h1all[KNN][64];
    #pragma unroll
    for (int k = 0; k < KNN; ++k) {
        const int m = idx[bn * KNN + k];
        const float* f = pts + ((size_t)b * NPTS + m) * 3;
        const float e0 = f[0] - cx, e1 = f[1] - cy, e2 = f[2] - cz;
        float a = w1r[0] * e0 + w1r[1] * e1 + w1r[2] * e2
                + w1r[3] * cx + w1r[4] * cy + w1r[5] * cz;
        h1all[k][c] = lrelu(a * s1c + b1c);
    }
    __syncthreads();

    float a2[KNN];
    #pragma unroll
    for (int k = 0; k < KNN; ++k) a2[k] = 0.f;
    for (int j4 = 0; j4 < 16; ++j4) {
        float4 wv = *(const float4*)&w2[c * 64 + j4 * 4];
        #pragma unroll
        for (int k = 0; k < KNN; ++k) {
            float4 h4 = *(const float4*)&h1all[k][j4 * 4];
            a2[k] += wv.x * h4.x + wv.y * h4.y + wv.z * h4.z + wv.w * h4.w;
        }
    }
    float mx = -FLT_MAX;
    #pragma unroll
    for (int k = 0; k < KNN; ++k) mx = fmaxf(mx, lrelu(a2[k] * s2c + b2c));
    outt[(size_t)bn * 64 + c] = mx;
}

// ---------------- edge conv stage 2: feat64 -> (128) -> 64 -> 64 -> max_k ----------------
__global__ __launch_bounds__(64) void edgeconv2_kernel(
    const float* __restrict__ xin, const int* __restrict__ idx,
    const float* __restrict__ w3, const float* __restrict__ s3, const float* __restrict__ b3,
    const float* __restrict__ w4, const float* __restrict__ s4, const float* __restrict__ b4,
    float* __restrict__ outt) {
    const int bn = blockIdx.x;
    const int b  = bn / NPTS;
    const int c  = threadIdx.x;

    __shared__ float cen[64];
    __shared__ float fea[KNN][64];
    __shared__ float h1all[KNN][64];
    cen[c] = xin[(size_t)bn * 64 + c];
    #pragma unroll
    for (int k = 0; k < KNN; ++k) {
        const int m = idx[bn * KNN + k];
        fea[k][c] = xin[((size_t)b * NPTS + m) * 64 + c];
    }
    __syncthreads();

    float a[KNN];
    #pragma unroll
    for (int k = 0; k < KNN; ++k) a[k] = 0.f;
    float4 ab = {0.f, 0.f, 0.f, 0.f};
    for (int j4 = 0; j4 < 16; ++j4) {
        float4 wa = *(const float4*)&w3[c * 128 + j4 * 4];
        float4 wb = *(const float4*)&w3[c * 128 + 64 + j4 * 4];
        float4 c4 = *(const float4*)&cen[j4 * 4];
        ab.x += (wb.x - wa.x) * c4.x; ab.y += (wb.y - wa.y) * c4.y;
        ab.z += (wb.z - wa.z) * c4.z; ab.w += (wb.w - wa.w) * c4.w;
        #pragma unroll
        for (int k = 0; k < KNN; ++k) {
            float4 f4 = *(const float4*)&fea[k][j4 * 4];
            a[k] += wa.x * f4.x + wa.y * f4.y + wa.z * f4.z + wa.w * f4.w;
        }
    }
    const float abase = (ab.x + ab.y) + (ab.z + ab.w);
    const float s3c = s3[c], b3c = b3[c], s4c = s4[c], b4c = b4[c];
    #pragma unroll
    for (int k = 0; k < KNN; ++k) h1all[k][c] = lrelu((a[k] + abase) * s3c + b3c);
    __syncthreads();

    float a2[KNN];
    #pragma unroll
    for (int k = 0; k < KNN; ++k) a2[k] = 0.f;
    for (int j4 = 0; j4 < 16; ++j4) {
        float4 wv = *(const float4*)&w4[c * 64 + j4 * 4];
        #pragma unroll
        for (int k = 0; k < KNN; ++k) {
            float4 h4 = *(const float4*)&h1all[k][j4 * 4];
            a2[k] += wv.x * h4.x + wv.y * h4.y + wv.z * h4.z + wv.w * h4.w;
        }
    }
    float mx = -FLT_MAX;
    #pragma unroll
    for (int k = 0; k < KNN; ++k) mx = fmaxf(mx, lrelu(a2[k] * s4c + b4c));
    outt[(size_t)bn * 64 + c] = mx;
}

// ---------------- edge conv stage 3: feat64 -> (128) -> 64 -> max_k ----------------
__global__ __launch_bounds__(64) void edgeconv3_kernel(
    const float* __restrict__ xin, const int* __restrict__ idx,
    const float* __restrict__ w5, const float* __restrict__ s5, const float* __restrict__ b5,
    float* __restrict__ outt) {
    const int bn = blockIdx.x;
    const int b  = bn / NPTS;
    const int c  = threadIdx.x;

    __shared__ float cen[64];
    __shared__ float fea[KNN][64];
    cen[c] = xin[(size_t)bn * 64 + c];
    #pragma unroll
    for (int k = 0; k < KNN; ++k) {
        const int m = idx[bn * KNN + k];
        fea[k][c] = xin[((size_t)b * NPTS + m) * 64 + c];
    }
    __syncthreads();

    float a[KNN];
    #pragma unroll
    for (int k = 0; k < KNN; ++k) a[k] = 0.f;
    float4 ab = {0.f, 0.f, 0.f, 0.f};
    for (int j4 = 0; j4 < 16; ++j4) {
        float4 wa = *(const float4*)&w5[c * 128 + j4 * 4];
        float4 wb = *(const float4*)&w5[c * 128 + 64 + j4 * 4];
        float4 c4 = *(const float4*)&cen[j4 * 4];
        ab.x += (wb.x - wa.x) * c4.x; ab.y += (wb.y - wa.y) * c4.y;
        ab.z += (wb.z - wa.z) * c4.z; ab.w += (wb.w - wa.w) * c4.w;
        #pragma unroll
        for (int k = 0; k < KNN; ++k) {
            float4 f4 = *(const float4*)&fea[k][j4 * 4];
            a[k] += wa.x * f4.x + wa.y * f4.y + wa.z * f4.z + wa.w * f4.w;
        }
    }
    const float abase = (ab.x + ab.y) + (ab.z + ab.w);
    const float s5c = s5[c], b5c = b5[c];
    float mx = -FLT_MAX;
    #pragma unroll
    for (int k = 0; k < KNN; ++k) mx = fmaxf(mx, lrelu((a[k] + abase) * s5c + b5c));
    outt[(size_t)bn * 64 + c] = mx;
}

// ---------------- label branch: (16) -> 64 ----------------
__global__ __launch_bounds__(64) void catvet_kernel(
    const float* __restrict__ label,
    const float* __restrict__ w7, const float* __restrict__ s7, const float* __restrict__ b7,
    float* __restrict__ catv) {
    const int b = blockIdx.x, c = threadIdx.x;
    float a = 0.f;
    #pragma unroll
    for (int i = 0; i < 16; ++i) a += w7[c * 16 + i] * label[b * 16 + i];
    catv[b * 64 + c] = lrelu(a * s7[c] + b7[c]);
}

// ---------------- w6 transpose: w6t[k][c] = w6[c][k] (one-time, 768 KB) ----------------
__global__ void w6t_kernel(const float* __restrict__ w6, float* __restrict__ w6t) {
    int i = blockIdx.x * 256 + threadIdx.x;
    if (i >= 192 * 1024) return;
    int k = i >> 10, c = i & 1023;
    w6t[i] = w6[c * 192 + k];
}

// ---------------- global feature GEMM: raw max_n( w6 . x[n] ) per channel ----------------
constexpr int OPTS = 32;
__global__ __launch_bounds__(256) void out4max_kernel(
    const float* __restrict__ out1t, const float* __restrict__ out2t, const float* __restrict__ out3t,
    const float* __restrict__ w6t, float* __restrict__ partial) {
    const int blk = blockIdx.x;
    const int b   = blk >> 6;
    const int nt  = blk & 63;
    const int t   = threadIdx.x;

    __shared__ float xs[192 * OPTS];   // [k][p], 24 KB; reads are all-lane broadcasts
    for (int idx = t; idx < 192 * OPTS; idx += 256) {
        int p = idx / 192, r = idx - p * 192;
        const size_t gp = (size_t)b * NPTS + nt * OPTS + p;
        float val;
        if (r < 64)       val = out1t[gp * 64 + r];
        else if (r < 128) val = out2t[gp * 64 + (r - 64)];
        else              val = out3t[gp * 64 + (r - 128)];
        xs[r * OPTS + p] = val;
    }
    __syncthreads();

    float mx0 = -FLT_MAX, mx1 = -FLT_MAX, mx2 = -FLT_MAX, mx3 = -FLT_MAX;
    #pragma unroll
    for (int pg = 0; pg < OPTS / 16; ++pg) {
        float acc0[16], acc1[16], acc2[16], acc3[16];
        #pragma unroll
        for (int p = 0; p < 16; ++p) { acc0[p] = 0.f; acc1[p] = 0.f; acc2[p] = 0.f; acc3[p] = 0.f; }
        #pragma unroll 2
        for (int k = 0; k < 192; ++k) {
            float4 wv = *(const float4*)&w6t[(size_t)k * 1024 + t * 4];
            const float4* xr4 = (const float4*)&xs[k * OPTS + pg * 16];
            #pragma unroll
            for (int p4 = 0; p4 < 4; ++p4) {
                float4 xv = xr4[p4];
                acc0[p4 * 4 + 0] += wv.x * xv.x; acc0[p4 * 4 + 1] += wv.x * xv.y;
                acc0[p4 * 4 + 2] += wv.x * xv.z; acc0[p4 * 4 + 3] += wv.x * xv.w;
                acc1[p4 * 4 + 0] += wv.y * xv.x; acc1[p4 * 4 + 1] += wv.y * xv.y;
                acc1[p4 * 4 + 2] += wv.y * xv.z; acc1[p4 * 4 + 3] += wv.y * xv.w;
                acc2[p4 * 4 + 0] += wv.z * xv.x; acc2[p4 * 4 + 1] += wv.z * xv.y;
                acc2[p4 * 4 + 2] += wv.z * xv.z; acc2[p4 * 4 + 3] += wv.z * xv.w;
                acc3[p4 * 4 + 0] += wv.w * xv.x; acc3[p4 * 4 + 1] += wv.w * xv.y;
                acc3[p4 * 4 + 2] += wv.w * xv.z; acc3[p4 * 4 + 3] += wv.w * xv.w;
            }
        }
        #pragma unroll
        for (int p = 0; p < 16; ++p) {
            mx0 = fmaxf(mx0, acc0[p]); mx1 = fmaxf(mx1, acc1[p]);
            mx2 = fmaxf(mx2, acc2[p]); mx3 = fmaxf(mx3, acc3[p]);
        }
    }
    float4 o = {mx0, mx1, mx2, mx3};
    *(float4*)&partial[(size_t)blk * 1024 + t * 4] = o;
}

__global__ __launch_bounds__(256) void out4reduce_kernel(
    const float* __restrict__ partial,
    const float* __restrict__ s6, const float* __restrict__ b6,
    float* __restrict__ out4m) {
    const int i = blockIdx.x * 256 + threadIdx.x;  // 8192 = 8 * 1024
    const int b = i >> 10, c = i & 1023;
    float m = -FLT_MAX;
    for (int nt = 0; nt < 64; ++nt)
        m = fmaxf(m, partial[((size_t)b * 64 + nt) * 1024 + c]);
    out4m[i] = lrelu(m * s6[c] + b6[c]);
}

// ---------------- per-batch head bias: g[b][o] = wp1[o,192:1280] . [out4m;catv] ----------------
__global__ __launch_bounds__(256) void gbias_kernel(
    const float* __restrict__ out4m, const float* __restrict__ catv,
    const float* __restrict__ wp1, float* __restrict__ g) {
    const int b = blockIdx.x, t = threadIdx.x;
    __shared__ float v[1088];
    for (int i = t; i < 1088; i += 256)
        v[i] = (i < 1024) ? out4m[(size_t)b * 1024 + i] : catv[(size_t)b * 64 + (i - 1024)];
    __syncthreads();
    const float* w = wp1 + (size_t)t * 1280 + 192;
    float4 s4 = {0.f, 0.f, 0.f, 0.f};
    for (int i = 0; i < 272; ++i) {
        float4 wv = *(const float4*)&w[i * 4];
        float4 vv = *(const float4*)&v[i * 4];
        s4.x += wv.x * vv.x; s4.y += wv.y * vv.y; s4.z += wv.z * vv.z; s4.w += wv.w * vv.w;
    }
    g[(size_t)b * 256 + t] = (s4.x + s4.y) + (s4.z + s4.w);
}

// ---------------- per-point head (tiled GEMM): 192 -> 256 -> 256 -> 128 -> 6 ----------------
constexpr int HP = 16;   // points per block
constexpr int KC = 16;   // k-chunk

__global__ __launch_bounds__(256) void head_kernel(
    const float* __restrict__ out1t, const float* __restrict__ out2t, const float* __restrict__ out3t,
    const float* __restrict__ g,
    const float* __restrict__ wp1, const float* __restrict__ sp1, const float* __restrict__ bp1,
    const float* __restrict__ wp2, const float* __restrict__ sp2, const float* __restrict__ bp2,
    const float* __restrict__ wp3, const float* __restrict__ sp3, const float* __restrict__ bp3,
    const float* __restrict__ wp4, float* __restrict__ out) {
    const int p0 = blockIdx.x * HP;
    const int b  = p0 >> 11;
    const int t  = threadIdx.x;

    __shared__ float smA[4096];      // xs[192][16] then t2s[256][16]
    __shared__ float smB[4096];      // t1s[256][16] then t3s[128][16]
    __shared__ float smW[KC * 256];  // weight chunk, k-major

    for (int e = t; e < 192 * HP; e += 256) {
        int p = e / 192, k = e - p * 192;
        float val;
        if (k < 64)       val = out1t[((size_t)(p0 + p)) * 64 + k];
        else if (k < 128) val = out2t[((size_t)(p0 + p)) * 64 + (k - 64)];
        else              val = out3t[((size_t)(p0 + p)) * 64 + (k - 128)];
        smA[k * HP + p] = val;
    }

    const int og = t & 31;   // 8 outs each
    const int pg = t >> 5;   // 2 points each

    // ---- layer 1: 192 -> 256, acc init = per-batch g ----
    float acc[2][8];
    #pragma unroll
    for (int i = 0; i < 8; ++i) {
        float gv = g[(size_t)b * 256 + og * 8 + i];
        acc[0][i] = gv; acc[1][i] = gv;
    }
    for (int kc = 0; kc < 192 / KC; ++kc) {
        __syncthreads();
        #pragma unroll
        for (int it = 0; it < KC; ++it)
            smW[it * 256 + t] = wp1[(size_t)t * 1280 + kc * KC + it];
        __syncthreads();
        #pragma unroll 4
        for (int kk = 0; kk < KC; ++kk) {
            int k = kc * KC + kk;
            float2 xv = *(const float2*)&smA[k * HP + pg * 2];
            float4 w0 = *(const float4*)&smW[kk * 256 + og * 8];
            float4 w1v = *(const float4*)&smW[kk * 256 + og * 8 + 4];
            float wv[8] = {w0.x, w0.y, w0.z, w0.w, w1v.x, w1v.y, w1v.z, w1v.w};
            #pragma unroll
            for (int i = 0; i < 8; ++i) {
                acc[0][i] += xv.x * wv[i];
                acc[1][i] += xv.y * wv[i];
            }
        }
    }
    #pragma unroll
    for (int i = 0; i < 8; ++i) {
        int o = og * 8 + i;
        float sc = sp1[o], bc = bp1[o];
        smB[o * HP + pg * 2 + 0] = lrelu(acc[0][i] * sc + bc);
        smB[o * HP + pg * 2 + 1] = lrelu(acc[1][i] * sc + bc);
    }

    // ---- layer 2: 256 -> 256 ----
    float acc2[2][8];
    #pragma unroll
    for (int i = 0; i < 8; ++i) { acc2[0][i] = 0.f; acc2[1][i] = 0.f; }
    for (int kc = 0; kc < 256 / KC; ++kc) {
        __syncthreads();
        #pragma unroll
        for (int it = 0; it < KC; ++it)
            smW[it * 256 + t] = wp2[(size_t)t * 256 + kc * KC + it];
        __syncthreads();
        #pragma unroll 4
        for (int kk = 0; kk < KC; ++kk) {
            int k = kc * KC + kk;
            float2 xv = *(const float2*)&smB[k * HP + pg * 2];
            float4 w0 = *(const float4*)&smW[kk * 256 + og * 8];
            float4 w1v = *(const float4*)&smW[kk * 256 + og * 8 + 4];
            float wv[8] = {w0.x, w0.y, w0.z, w0.w, w1v.x, w1v.y, w1v.z, w1v.w};
            #pragma unroll
            for (int i = 0; i < 8; ++i) {
                acc2[0][i] += xv.x * wv[i];
                acc2[1][i] += xv.y * wv[i];
            }
        }
    }
    __syncthreads();
    #pragma unroll
    for (int i = 0; i < 8; ++i) {
        int o = og * 8 + i;
        float sc = sp2[o], bc = bp2[o];
        smA[o * HP + pg * 2 + 0] = lrelu(acc2[0][i] * sc + bc);
        smA[o * HP + pg * 2 + 1] = lrelu(acc2[1][i] * sc + bc);
    }

    // ---- layer 3: 256 -> 128 ----
    const int og3 = t & 15;
    const int p3  = t >> 4;
    float acc3[8];
    #pragma unroll
    for (int i = 0; i < 8; ++i) acc3[i] = 0.f;
    for (int kc = 0; kc < 256 / KC; ++kc) {
        __syncthreads();
        for (int e = t; e < KC * 128; e += 256) {
            int kk = e >> 7, o = e & 127;
            smW[kk * 128 + o] = wp3[(size_t)o * 256 + kc * KC + kk];
        }
        __syncthreads();
        #pragma unroll 4
        for (int kk = 0; kk < KC; ++kk) {
            int k = kc * KC + kk;
            float xv = smA[k * HP + p3];
            float4 w0 = *(const float4*)&smW[kk * 128 + og3 * 8];
            float4 w1v = *(const float4*)&smW[kk * 128 + og3 * 8 + 4];
            float wv[8] = {w0.x, w0.y, w0.z, w0.w, w1v.x, w1v.y, w1v.z, w1v.w};
            #pragma unroll
            for (int i = 0; i < 8; ++i) acc3[i] += xv * wv[i];
        }
    }
    __syncthreads();
    #pragma unroll
    for (int i = 0; i < 8; ++i) {
        int o = og3 * 8 + i;
        float sc = sp3[o], bc = bp3[o];
        smB[o * HP + p3] = lrelu(acc3[i] * sc + bc);
    }
    __syncthreads();

    // ---- layer 4: 128 -> 6 ----
    if (t < HP * 6) {
        int p = t / 6, o = t - p * 6;
        float4 s4 = {0.f, 0.f, 0.f, 0.f};
        for (int k4 = 0; k4 < 32; ++k4) {
            float4 wv = *(const float4*)&wp4[o * 128 + k4 * 4];
            s4.x += wv.x * smB[(k4 * 4 + 0) * HP + p];
            s4.y += wv.y * smB[(k4 * 4 + 1) * HP + p];
            s4.z += wv.z * smB[(k4 * 4 + 2) * HP + p];
            s4.w += wv.w * smB[(k4 * 4 + 3) * HP + p];
        }
        out[((size_t)(p0 + p)) * 6 + o] = (s4.x + s4.y) + (s4.z + s4.w);
    }
}

extern "C" void kernel_launch(void* const* d_in, const int* in_sizes, int n_in,
                              void* d_out, int out_size, void* d_ws, size_t ws_size,
                              hipStream_t stream) {
    const float* points = (const float*)d_in[0];
    const float* label  = (const float*)d_in[1];
    const float* w1  = (const float*)d_in[2];
    const float* s1  = (const float*)d_in[3];
    const float* b1  = (const float*)d_in[4];
    const float* w2  = (const float*)d_in[5];
    const float* s2  = (const float*)d_in[6];
    const float* b2  = (const float*)d_in[7];
    const float* w3  = (const float*)d_in[8];
    const float* s3  = (const float*)d_in[9];
    const float* b3  = (const float*)d_in[10];
    const float* w4  = (const float*)d_in[11];
    const float* s4  = (const float*)d_in[12];
    const float* b4  = (const float*)d_in[13];
    const float* w5  = (const float*)d_in[14];
    const float* s5  = (const float*)d_in[15];
    const float* b5  = (const float*)d_in[16];
    const float* w6  = (const float*)d_in[17];
    const float* s6  = (const float*)d_in[18];
    const float* b6  = (const float*)d_in[19];
    const float* w7  = (const float*)d_in[20];
    const float* s7  = (const float*)d_in[21];
    const float* b7  = (const float*)d_in[22];
    const float* wp1 = (const float*)d_in[23];
    const float* sp1 = (const float*)d_in[24];
    const float* bp1 = (const float*)d_in[25];
    const float* wp2 = (const float*)d_in[26];
    const float* sp2 = (const float*)d_in[27];
    const float* bp2 = (const float*)d_in[28];
    const float* wp3 = (const float*)d_in[29];
    const float* sp3 = (const float*)d_in[30];
    const float* bp3 = (const float*)d_in[31];
    const float* wp4 = (const float*)d_in[32];

    float* ws = (float*)d_ws;
    size_t off = 0;
    auto alloc = [&](size_t nf) { float* p = ws + off; off += nf; return p; };
    float* out1t = alloc((size_t)BATCH * NPTS * 64);
    float* out2t = alloc((size_t)BATCH * NPTS * 64);
    float* out3t = alloc((size_t)BATCH * NPTS * 64);
    float* sqb   = alloc((size_t)BATCH * NPTS);
    float* out4m = alloc((size_t)BATCH * 1024);
    float* catv  = alloc((size_t)BATCH * 64);
    float* gb    = alloc((size_t)BATCH * 256);
    float* w6t   = alloc((size_t)192 * 1024);
    float* part  = alloc((size_t)512 * 1024);
    int* idx1 = (int*)alloc((size_t)BATCH * NPTS * KNN);
    int* idx2 = (int*)alloc((size_t)BATCH * NPTS * KNN);
    int* idx3 = (int*)alloc((size_t)BATCH * NPTS * KNN);

    const int BN = BATCH * NPTS;
    const int sqBlocks = (BN + 255) / 256;

    // stage 1
    sq_kernel<3><<<sqBlocks, 256, 0, stream>>>(points, sqb);
    knn_kernel<3><<<BN, 256, 0, stream>>>(points, sqb, idx1);
    edgeconv1_kernel<<<BN, 64, 0, stream>>>(points, idx1, w1, s1, b1, w2, s2, b2, out1t);

    // stage 2
    sq64_kernel<<<sqBlocks, 256, 0, stream>>>(out1t, sqb);
    knn64_kernel<<<BN / 8, 256, 0, stream>>>(out1t, sqb, idx2);
    edgeconv2_kernel<<<BN, 64, 0, stream>>>(out1t, idx2, w3, s3, b3, w4, s4, b4, out2t);

    // stage 3
    sq64_kernel<<<sqBlocks, 256, 0, stream>>>(out2t, sqb);
    knn64_kernel<<<BN / 8, 256, 0, stream>>>(out2t, sqb, idx3);
    edgeconv3_kernel<<<BN, 64, 0, stream>>>(out2t, idx3, w5, s5, b5, out3t);

    // global branches
    catvet_kernel<<<BATCH, 64, 0, stream>>>(label, w7, s7, b7, catv);
    w6t_kernel<<<(192 * 1024 + 255) / 256, 256, 0, stream>>>(w6, w6t);
    out4max_kernel<<<512, 256, 0, stream>>>(out1t, out2t, out3t, w6t, part);
    out4reduce_kernel<<<BATCH * 1024 / 256, 256, 0, stream>>>(part, s6, b6, out4m);
    gbias_kernel<<<BATCH, 256, 0, stream>>>(out4m, catv, wp1, gb);

    // head
    head_kernel<<<BN / HP, 256, 0, stream>>>(out1t, out2t, out3t, gb,
                                             wp1, sp1, bp1, wp2, sp2, bp2, wp3, sp3, bp3,
                                             wp4, (float*)d_out);
}

// Round 8
// 1116.336 us; speedup vs baseline: 2.0146x; 1.0341x over previous
//
#include <hip/hip_runtime.h>
#include <float.h>

#define NEG 0.2f
constexpr int BATCH = 8;
constexpr int NPTS  = 2048;
constexpr int KNN   = 10;
constexpr int KP1   = 11;

__device__ __forceinline__ float lrelu(float x) { return x > 0.f ? x : NEG * x; }

// ordered-u64 key: (monotone uint of d2) << 32 | idx  => u64 '<' == (d2 asc, idx asc)
__device__ __forceinline__ unsigned long long dkey(float d, int m) {
    unsigned u = __float_as_uint(d);
    u ^= (unsigned)((int)u >> 31) | 0x80000000u;
    return ((unsigned long long)u << 32) | (unsigned)m;
}

// ---------------- squared-norm per point ----------------
template<int D>
__global__ void sq_kernel(const float* __restrict__ xt, float* __restrict__ sq) {
    int i = blockIdx.x * 256 + threadIdx.x;
    if (i >= BATCH * NPTS) return;
    const float* p = xt + (size_t)i * D;
    float s = 0.f;
    #pragma unroll
    for (int d = 0; d < D; ++d) s += p[d] * p[d];
    sq[i] = s;
}

__global__ void sq64_kernel(const float* __restrict__ xt, float* __restrict__ sq) {
    int i = blockIdx.x * 256 + threadIdx.x;
    if (i >= BATCH * NPTS) return;
    const float4* p = (const float4*)(xt + (size_t)i * 64);
    float4 s4 = {0.f, 0.f, 0.f, 0.f};
    #pragma unroll
    for (int d = 0; d < 16; ++d) {
        float4 v = p[d];
        s4.x += v.x * v.x; s4.y += v.y * v.y; s4.z += v.z * v.z; s4.w += v.w * v.w;
    }
    sq[i] = (s4.x + s4.y) + (s4.z + s4.w);
}

// ---------------- kNN D=3: one WAVE per (b,n); register top-11 + shuffle extraction ----------------
__global__ __launch_bounds__(64) void knn3_kernel(const float* __restrict__ xt,
                                                  const float* __restrict__ sq,
                                                  int* __restrict__ idx_out) {
    const int bn = blockIdx.x;
    const int b  = bn >> 11;           // NPTS = 2048
    const int l  = threadIdx.x;

    const float qx = xt[(size_t)bn * 3 + 0];
    const float qy = xt[(size_t)bn * 3 + 1];
    const float qz = xt[(size_t)bn * 3 + 2];
    const float sqn = sq[bn];
    const float* xb  = xt + (size_t)b * NPTS * 3;
    const float* sqb_ = sq + (size_t)b * NPTS;

    unsigned long long lk[KP1];
    #pragma unroll
    for (int j = 0; j < KP1; ++j) lk[j] = ~0ULL;

    for (int m = l; m < NPTS; m += 64) {
        // same fma chain as before: ((0+qx*x)+qy*y)+qz*z
        float dot = 0.f;
        dot += qx * xb[m * 3 + 0];
        dot += qy * xb[m * 3 + 1];
        dot += qz * xb[m * 3 + 2];
        float cd = sqn + sqb_[m] - 2.f * dot;
        unsigned long long key = dkey(cd, m);
        if (key < lk[KP1 - 1]) {
            #pragma unroll
            for (int j = 0; j < KP1; ++j) {
                bool better = key < lk[j];
                unsigned long long tk = lk[j];
                if (better) { lk[j] = key; key = tk; }
            }
        }
    }

    // width-64 min-extraction: 11 ascending unique keys == merged top-11
    #pragma unroll
    for (int k = 0; k < KP1; ++k) {
        unsigned long long mk = lk[0];
        #pragma unroll
        for (int s = 32; s >= 1; s >>= 1) {
            unsigned long long o = __shfl_xor(mk, s, 64);
            mk = (o < mk) ? o : mk;
        }
        if (k >= 1 && l == k - 1)
            idx_out[(size_t)bn * KNN + (k - 1)] = (int)(unsigned)mk;
        if (lk[0] == mk) {   // unique winner pops (static shift)
            #pragma unroll
            for (int j = 0; j < KP1 - 1; ++j) lk[j] = lk[j + 1];
            lk[KP1 - 1] = ~0ULL;
        }
    }
}

// ---------------- kNN D=64: 8 queries/block, XOR-swizzled f4 tile + shuffle extraction ----------------
// Dot accumulation order (a0..a3 by dim%4) identical to verified version. Merge tree replaced
// by register min-extraction per 32-lane group: no merge LDS, no conflicts, no post-loop barriers.
__global__ __launch_bounds__(256) void knn64_kernel(const float* __restrict__ xt,
                                                    const float* __restrict__ sq,
                                                    int* __restrict__ idx_out) {
    const int t  = threadIdx.x;
    const int qg = t >> 5;   // query within block (0..7)
    const int lc = t & 31;   // candidate lane (0..31)
    const int bn0 = blockIdx.x * 8;
    const int bn  = bn0 + qg;
    const int b   = bn >> 11;          // NPTS = 2048
    const float* xb = xt + (size_t)b * NPTS * 64;

    __shared__ __align__(16) float4 tile4[32][16];   // 8 KB

    float4 xq[16];
    {
        const float4* xqp = (const float4*)(xt + (size_t)bn * 64);
        #pragma unroll
        for (int i = 0; i < 16; ++i) xq[i] = xqp[i];
    }
    const float sqn = sq[bn];
    const float* sqb_ = sq + b * NPTS;

    unsigned long long lk[KP1];
    #pragma unroll
    for (int j = 0; j < KP1; ++j) lk[j] = ~0ULL;

    const int ci  = t >> 3;   // staging: candidate within tile (0..31)
    const int sub = t & 7;    // staging: 8-dim slice (2 f4 slots)

    for (int t0 = 0; t0 < NPTS; t0 += 32) {
        __syncthreads();   // protect previous tile reads
        {
            const float4* src = (const float4*)(xb + (size_t)(t0 + ci) * 64 + sub * 8);
            float4 u0 = src[0], u1 = src[1];
            tile4[ci][(2 * sub)     ^ (ci & 15)] = u0;
            tile4[ci][(2 * sub + 1) ^ (ci & 15)] = u1;
        }
        __syncthreads();

        const int m = t0 + lc;
        float a0 = 0.f, a1 = 0.f, a2 = 0.f, a3 = 0.f;
        #pragma unroll
        for (int i = 0; i < 16; ++i) {
            float4 v = tile4[lc][i ^ (lc & 15)];
            a0 += xq[i].x * v.x;
            a1 += xq[i].y * v.y;
            a2 += xq[i].z * v.z;
            a3 += xq[i].w * v.w;
        }
        float dot = (a0 + a1) + (a2 + a3);
        float cd = sqn + sqb_[m] - 2.f * dot;
        unsigned long long key = dkey(cd, m);
        if (key < lk[KP1 - 1]) {
            #pragma unroll
            for (int j = 0; j < KP1; ++j) {
                bool better = key < lk[j];
                unsigned long long tk = lk[j];
                if (better) { lk[j] = key; key = tk; }
            }
        }
    }

    // width-32 min-extraction within each query group (keys unique -> one pop/iter)
    #pragma unroll
    for (int k = 0; k < KP1; ++k) {
        unsigned long long mk = lk[0];
        #pragma unroll
        for (int s = 16; s >= 1; s >>= 1) {
            unsigned long long o = __shfl_xor(mk, s, 32);
            mk = (o < mk) ? o : mk;
        }
        if (k >= 1 && lc == k - 1)
            idx_out[(size_t)bn * KNN + (k - 1)] = (int)(unsigned)mk;
        if (lk[0] == mk) {
            #pragma unroll
            for (int j = 0; j < KP1 - 1; ++j) lk[j] = lk[j + 1];
            lk[KP1 - 1] = ~0ULL;
        }
    }
}

// ---------------- edge conv stage 1: points(3) -> 64 -> 64 -> max_k ----------------
__global__ __launch_bounds__(64) void edgeconv1_kernel(
    const float* __restrict__ pts, const int* __restrict__ idx,
    const float* __restrict__ w1, const float* __restrict__ s1, const float* __restrict__ b1,
    const float* __restrict__ w2, const float* __restrict__ s2, const float* __restrict__ b2,
    float* __restrict__ outt) {
    const int bn = blockIdx.x;
    const int b  = bn / NPTS;
    const int c  = threadIdx.x;

    const float cx = pts[bn * 3 + 0], cy = pts[bn * 3 + 1], cz = pts[bn * 3 + 2];

    float w1r[6];
    #pragma unroll
    for (int i = 0; i < 6; ++i) w1r[i] = w1[c * 6 + i];
    const float s1c = s1[c], b1c = b1[c], s2c = s2[c], b2c = b2[c];

    __shared__ float h1all[KNN][64];
    #pragma unroll
    for (int k = 0; k < KNN; ++k) {
        const int m = idx[bn * KNN + k];
        const float* f = pts + ((size_t)b * NPTS + m) * 3;
        const float e0 = f[0] - cx, e1 = f[1] - cy, e2 = f[2] - cz;
        float a = w1r[0] * e0 + w1r[1] * e1 + w1r[2] * e2
                + w1r[3] * cx + w1r[4] * cy + w1r[5] * cz;
        h1all[k][c] = lrelu(a * s1c + b1c);
    }
    __syncthreads();

    float a2[KNN];
    #pragma unroll
    for (int k = 0; k < KNN; ++k) a2[k] = 0.f;
    for (int j4 = 0; j4 < 16; ++j4) {
        float4 wv = *(const float4*)&w2[c * 64 + j4 * 4];
        #pragma unroll
        for (int k = 0; k < KNN; ++k) {
            float4 h4 = *(const float4*)&h1all[k][j4 * 4];
            a2[k] += wv.x * h4.x + wv.y * h4.y + wv.z * h4.z + wv.w * h4.w;
        }
    }
    float mx = -FLT_MAX;
    #pragma unroll
    for (int k = 0; k < KNN; ++k) mx = fmaxf(mx, lrelu(a2[k] * s2c + b2c));
    outt[(size_t)bn * 64 + c] = mx;
}

// ---------------- edge conv stage 2: feat64 -> (128) -> 64 -> 64 -> max_k ----------------
__global__ __launch_bounds__(64) void edgeconv2_kernel(
    const float* __restrict__ xin, const int* __restrict__ idx,
    const float* __restrict__ w3, const float* __restrict__ s3, const float* __restrict__ b3,
    const float* __restrict__ w4, const float* __restrict__ s4, const float* __restrict__ b4,
    float* __restrict__ outt) {
    const int bn = blockIdx.x;
    const int b  = bn / NPTS;
    const int c  = threadIdx.x;

    __shared__ float cen[64];
    __shared__ float fea[KNN][64];
    __shared__ float h1all[KNN][64];
    cen[c] = xin[(size_t)bn * 64 + c];
    #pragma unroll
    for (int k = 0; k < KNN; ++k) {
        const int m = idx[bn * KNN + k];
        fea[k][c] = xin[((size_t)b * NPTS + m) * 64 + c];
    }
    __syncthreads();

    float a[KNN];
    #pragma unroll
    for (int k = 0; k < KNN; ++k) a[k] = 0.f;
    float4 ab = {0.f, 0.f, 0.f, 0.f};
    for (int j4 = 0; j4 < 16; ++j4) {
        float4 wa = *(const float4*)&w3[c * 128 + j4 * 4];
        float4 wb = *(const float4*)&w3[c * 128 + 64 + j4 * 4];
        float4 c4 = *(const float4*)&cen[j4 * 4];
        ab.x += (wb.x - wa.x) * c4.x; ab.y += (wb.y - wa.y) * c4.y;
        ab.z += (wb.z - wa.z) * c4.z; ab.w += (wb.w - wa.w) * c4.w;
        #pragma unroll
        for (int k = 0; k < KNN; ++k) {
            float4 f4 = *(const float4*)&fea[k][j4 * 4];
            a[k] += wa.x * f4.x + wa.y * f4.y + wa.z * f4.z + wa.w * f4.w;
        }
    }
    const float abase = (ab.x + ab.y) + (ab.z + ab.w);
    const float s3c = s3[c], b3c = b3[c], s4c = s4[c], b4c = b4[c];
    #pragma unroll
    for (int k = 0; k < KNN; ++k) h1all[k][c] = lrelu((a[k] + abase) * s3c + b3c);
    __syncthreads();

    float a2[KNN];
    #pragma unroll
    for (int k = 0; k < KNN; ++k) a2[k] = 0.f;
    for (int j4 = 0; j4 < 16; ++j4) {
        float4 wv = *(const float4*)&w4[c * 64 + j4 * 4];
        #pragma unroll
        for (int k = 0; k < KNN; ++k) {
            float4 h4 = *(const float4*)&h1all[k][j4 * 4];
            a2[k] += wv.x * h4.x + wv.y * h4.y + wv.z * h4.z + wv.w * h4.w;
        }
    }
    float mx = -FLT_MAX;
    #pragma unroll
    for (int k = 0; k < KNN; ++k) mx = fmaxf(mx, lrelu(a2[k] * s4c + b4c));
    outt[(size_t)bn * 64 + c] = mx;
}

// ---------------- edge conv stage 3: feat64 -> (128) -> 64 -> max_k ----------------
__global__ __launch_bounds__(64) void edgeconv3_kernel(
    const float* __restrict__ xin, const int* __restrict__ idx,
    const float* __restrict__ w5, const float* __restrict__ s5, const float* __restrict__ b5,
    float* __restrict__ outt) {
    const int bn = blockIdx.x;
    const int b  = bn / NPTS;
    const int c  = threadIdx.x;

    __shared__ float cen[64];
    __shared__ float fea[KNN][64];
    cen[c] = xin[(size_t)bn * 64 + c];
    #pragma unroll
    for (int k = 0; k < KNN; ++k) {
        const int m = idx[bn * KNN + k];
        fea[k][c] = xin[((size_t)b * NPTS + m) * 64 + c];
    }
    __syncthreads();

    float a[KNN];
    #pragma unroll
    for (int k = 0; k < KNN; ++k) a[k] = 0.f;
    float4 ab = {0.f, 0.f, 0.f, 0.f};
    for (int j4 = 0; j4 < 16; ++j4) {
        float4 wa = *(const float4*)&w5[c * 128 + j4 * 4];
        float4 wb = *(const float4*)&w5[c * 128 + 64 + j4 * 4];
        float4 c4 = *(const float4*)&cen[j4 * 4];
        ab.x += (wb.x - wa.x) * c4.x; ab.y += (wb.y - wa.y) * c4.y;
        ab.z += (wb.z - wa.z) * c4.z; ab.w += (wb.w - wa.w) * c4.w;
        #pragma unroll
        for (int k = 0; k < KNN; ++k) {
            float4 f4 = *(const float4*)&fea[k][j4 * 4];
            a[k] += wa.x * f4.x + wa.y * f4.y + wa.z * f4.z + wa.w * f4.w;
        }
    }
    const float abase = (ab.x + ab.y) + (ab.z + ab.w);
    const float s5c = s5[c], b5c = b5[c];
    float mx = -FLT_MAX;
    #pragma unroll
    for (int k = 0; k < KNN; ++k) mx = fmaxf(mx, lrelu((a[k] + abase) * s5c + b5c));
    outt[(size_t)bn * 64 + c] = mx;
}

// ---------------- label branch: (16) -> 64 ----------------
__global__ __launch_bounds__(64) void catvet_kernel(
    const float* __restrict__ label,
    const float* __restrict__ w7, const float* __restrict__ s7, const float* __restrict__ b7,
    float* __restrict__ catv) {
    const int b = blockIdx.x, c = threadIdx.x;
    float a = 0.f;
    #pragma unroll
    for (int i = 0; i < 16; ++i) a += w7[c * 16 + i] * label[b * 16 + i];
    catv[b * 64 + c] = lrelu(a * s7[c] + b7[c]);
}

// ---------------- w6 transpose: w6t[k][c] = w6[c][k] (one-time, 768 KB) ----------------
__global__ void w6t_kernel(const float* __restrict__ w6, float* __restrict__ w6t) {
    int i = blockIdx.x * 256 + threadIdx.x;
    if (i >= 192 * 1024) return;
    int k = i >> 10, c = i & 1023;
    w6t[i] = w6[c * 192 + k];
}

// ---------------- global feature GEMM: raw max_n( w6 . x[n] ) per channel ----------------
constexpr int OPTS = 32;
__global__ __launch_bounds__(256) void out4max_kernel(
    const float* __restrict__ out1t, const float* __restrict__ out2t, const float* __restrict__ out3t,
    const float* __restrict__ w6t, float* __restrict__ partial) {
    const int blk = blockIdx.x;
    const int b   = blk >> 6;
    const int nt  = blk & 63;
    const int t   = threadIdx.x;

    __shared__ float xs[192 * OPTS];   // [k][p], 24 KB; reads are all-lane broadcasts
    for (int idx = t; idx < 192 * OPTS; idx += 256) {
        int p = idx / 192, r = idx - p * 192;
        const size_t gp = (size_t)b * NPTS + nt * OPTS + p;
        float val;
        if (r < 64)       val = out1t[gp * 64 + r];
        else if (r < 128) val = out2t[gp * 64 + (r - 64)];
        else              val = out3t[gp * 64 + (r - 128)];
        xs[r * OPTS + p] = val;
    }
    __syncthreads();

    float mx0 = -FLT_MAX, mx1 = -FLT_MAX, mx2 = -FLT_MAX, mx3 = -FLT_MAX;
    #pragma unroll
    for (int pg = 0; pg < OPTS / 16; ++pg) {
        float acc0[16], acc1[16], acc2[16], acc3[16];
        #pragma unroll
        for (int p = 0; p < 16; ++p) { acc0[p] = 0.f; acc1[p] = 0.f; acc2[p] = 0.f; acc3[p] = 0.f; }
        #pragma unroll 2
        for (int k = 0; k < 192; ++k) {
            float4 wv = *(const float4*)&w6t[(size_t)k * 1024 + t * 4];
            const float4* xr4 = (const float4*)&xs[k * OPTS + pg * 16];
            #pragma unroll
            for (int p4 = 0; p4 < 4; ++p4) {
                float4 xv = xr4[p4];
                acc0[p4 * 4 + 0] += wv.x * xv.x; acc0[p4 * 4 + 1] += wv.x * xv.y;
                acc0[p4 * 4 + 2] += wv.x * xv.z; acc0[p4 * 4 + 3] += wv.x * xv.w;
                acc1[p4 * 4 + 0] += wv.y * xv.x; acc1[p4 * 4 + 1] += wv.y * xv.y;
                acc1[p4 * 4 + 2] += wv.y * xv.z; acc1[p4 * 4 + 3] += wv.y * xv.w;
                acc2[p4 * 4 + 0] += wv.z * xv.x; acc2[p4 * 4 + 1] += wv.z * xv.y;
                acc2[p4 * 4 + 2] += wv.z * xv.z; acc2[p4 * 4 + 3] += wv.z * xv.w;
                acc3[p4 * 4 + 0] += wv.w * xv.x; acc3[p4 * 4 + 1] += wv.w * xv.y;
                acc3[p4 * 4 + 2] += wv.w * xv.z; acc3[p4 * 4 + 3] += wv.w * xv.w;
            }
        }
        #pragma unroll
        for (int p = 0; p < 16; ++p) {
            mx0 = fmaxf(mx0, acc0[p]); mx1 = fmaxf(mx1, acc1[p]);
            mx2 = fmaxf(mx2, acc2[p]); mx3 = fmaxf(mx3, acc3[p]);
        }
    }
    float4 o = {mx0, mx1, mx2, mx3};
    *(float4*)&partial[(size_t)blk * 1024 + t * 4] = o;
}

__global__ __launch_bounds__(256) void out4reduce_kernel(
    const float* __restrict__ partial,
    const float* __restrict__ s6, const float* __restrict__ b6,
    float* __restrict__ out4m) {
    const int i = blockIdx.x * 256 + threadIdx.x;  // 8192 = 8 * 1024
    const int b = i >> 10, c = i & 1023;
    float m = -FLT_MAX;
    for (int nt = 0; nt < 64; ++nt)
        m = fmaxf(m, partial[((size_t)b * 64 + nt) * 1024 + c]);
    out4m[i] = lrelu(m * s6[c] + b6[c]);
}

// ---------------- per-batch head bias: g[b][o] = wp1[o,192:1280] . [out4m;catv] ----------------
__global__ __launch_bounds__(256) void gbias_kernel(
    const float* __restrict__ out4m, const float* __restrict__ catv,
    const float* __restrict__ wp1, float* __restrict__ g) {
    const int b = blockIdx.x, t = threadIdx.x;
    __shared__ float v[1088];
    for (int i = t; i < 1088; i += 256)
        v[i] = (i < 1024) ? out4m[(size_t)b * 1024 + i] : catv[(size_t)b * 64 + (i - 1024)];
    __syncthreads();
    const float* w = wp1 + (size_t)t * 1280 + 192;
    float4 s4 = {0.f, 0.f, 0.f, 0.f};
    for (int i = 0; i < 272; ++i) {
        float4 wv = *(const float4*)&w[i * 4];
        float4 vv = *(const float4*)&v[i * 4];
        s4.x += wv.x * vv.x; s4.y += wv.y * vv.y; s4.z += wv.z * vv.z; s4.w += wv.w * vv.w;
    }
    g[(size_t)b * 256 + t] = (s4.x + s4.y) + (s4.z + s4.w);
}

// ---------------- per-point head (tiled GEMM): 192 -> 256 -> 256 -> 128 -> 6 ----------------
constexpr int HP = 16;   // points per block
constexpr int KC = 16;   // k-chunk

__global__ __launch_bounds__(256) void head_kernel(
    const float* __restrict__ out1t, const float* __restrict__ out2t, const float* __restrict__ out3t,
    const float* __restrict__ g,
    const float* __restrict__ wp1, const float* __restrict__ sp1, const float* __restrict__ bp1,
    const float* __restrict__ wp2, const float* __restrict__ sp2, const float* __restrict__ bp2,
    const float* __restrict__ wp3, const float* __restrict__ sp3, const float* __restrict__ bp3,
    const float* __restrict__ wp4, float* __restrict__ out) {
    const int p0 = blockIdx.x * HP;
    const int b  = p0 >> 11;
    const int t  = threadIdx.x;

    __shared__ float smA[4096];      // xs[192][16] then t2s[256][16]
    __shared__ float smB[4096];      // t1s[256][16] then t3s[128][16]
    __shared__ float smW[KC * 256];  // weight chunk, k-major

    for (int e = t; e < 192 * HP; e += 256) {
        int p = e / 192, k = e - p * 192;
        float val;
        if (k < 64)       val = out1t[((size_t)(p0 + p)) * 64 + k];
        else if (k < 128) val = out2t[((size_t)(p0 + p)) * 64 + (k - 64)];
        else              val = out3t[((size_t)(p0 + p)) * 64 + (k - 128)];
        smA[k * HP + p] = val;
    }

    const int og = t & 31;   // 8 outs each
    const int pg = t >> 5;   // 2 points each

    // ---- layer 1: 192 -> 256, acc init = per-batch g ----
    float acc[2][8];
    #pragma unroll
    for (int i = 0; i < 8; ++i) {
        float gv = g[(size_t)b * 256 + og * 8 + i];
        acc[0][i] = gv; acc[1][i] = gv;
    }
    for (int kc = 0; kc < 192 / KC; ++kc) {
        __syncthreads();
        #pragma unroll
        for (int it = 0; it < KC; ++it)
            smW[it * 256 + t] = wp1[(size_t)t * 1280 + kc * KC + it];
        __syncthreads();
        #pragma unroll 4
        for (int kk = 0; kk < KC; ++kk) {
            int k = kc * KC + kk;
            float2 xv = *(const float2*)&smA[k * HP + pg * 2];
            float4 w0 = *(const float4*)&smW[kk * 256 + og * 8];
            float4 w1v = *(const float4*)&smW[kk * 256 + og * 8 + 4];
            float wv[8] = {w0.x, w0.y, w0.z, w0.w, w1v.x, w1v.y, w1v.z, w1v.w};
            #pragma unroll
            for (int i = 0; i < 8; ++i) {
                acc[0][i] += xv.x * wv[i];
                acc[1][i] += xv.y * wv[i];
            }
        }
    }
    #pragma unroll
    for (int i = 0; i < 8; ++i) {
        int o = og * 8 + i;
        float sc = sp1[o], bc = bp1[o];
        smB[o * HP + pg * 2 + 0] = lrelu(acc[0][i] * sc + bc);
        smB[o * HP + pg * 2 + 1] = lrelu(acc[1][i] * sc + bc);
    }

    // ---- layer 2: 256 -> 256 ----
    float acc2[2][8];
    #pragma unroll
    for (int i = 0; i < 8; ++i) { acc2[0][i] = 0.f; acc2[1][i] = 0.f; }
    for (int kc = 0; kc < 256 / KC; ++kc) {
        __syncthreads();
        #pragma unroll
        for (int it = 0; it < KC; ++it)
            smW[it * 256 + t] = wp2[(size_t)t * 256 + kc * KC + it];
        __syncthreads();
        #pragma unroll 4
        for (int kk = 0; kk < KC; ++kk) {
            int k = kc * KC + kk;
            float2 xv = *(const float2*)&smB[k * HP + pg * 2];
            float4 w0 = *(const float4*)&smW[kk * 256 + og * 8];
            float4 w1v = *(const float4*)&smW[kk * 256 + og * 8 + 4];
            float wv[8] = {w0.x, w0.y, w0.z, w0.w, w1v.x, w1v.y, w1v.z, w1v.w};
            #pragma unroll
            for (int i = 0; i < 8; ++i) {
                acc2[0][i] += xv.x * wv[i];
                acc2[1][i] += xv.y * wv[i];
            }
        }
    }
    __syncthreads();
    #pragma unroll
    for (int i = 0; i < 8; ++i) {
        int o = og * 8 + i;
        float sc = sp2[o], bc = bp2[o];
        smA[o * HP + pg * 2 + 0] = lrelu(acc2[0][i] * sc + bc);
        smA[o * HP + pg * 2 + 1] = lrelu(acc2[1][i] * sc + bc);
    }

    // ---- layer 3: 256 -> 128 ----
    const int og3 = t & 15;
    const int p3  = t >> 4;
    float acc3[8];
    #pragma unroll
    for (int i = 0; i < 8; ++i) acc3[i] = 0.f;
    for (int kc = 0; kc < 256 / KC; ++kc) {
        __syncthreads();
        for (int e = t; e < KC * 128; e += 256) {
            int kk = e >> 7, o = e & 127;
            smW[kk * 128 + o] = wp3[(size_t)o * 256 + kc * KC + kk];
        }
        __syncthreads();
        #pragma unroll 4
        for (int kk = 0; kk < KC; ++kk) {
            int k = kc * KC + kk;
            float xv = smA[k * HP + p3];
            float4 w0 = *(const float4*)&smW[kk * 128 + og3 * 8];
            float4 w1v = *(const float4*)&smW[kk * 128 + og3 * 8 + 4];
            float wv[8] = {w0.x, w0.y, w0.z, w0.w, w1v.x, w1v.y, w1v.z, w1v.w};
            #pragma unroll
            for (int i = 0; i < 8; ++i) acc3[i] += xv * wv[i];
        }
    }
    __syncthreads();
    #pragma unroll
    for (int i = 0; i < 8; ++i) {
        int o = og3 * 8 + i;
        float sc = sp3[o], bc = bp3[o];
        smB[o * HP + p3] = lrelu(acc3[i] * sc + bc);
    }
    __syncthreads();

    // ---- layer 4: 128 -> 6 ----
    if (t < HP * 6) {
        int p = t / 6, o = t - p * 6;
        float4 s4 = {0.f, 0.f, 0.f, 0.f};
        for (int k4 = 0; k4 < 32; ++k4) {
            float4 wv = *(const float4*)&wp4[o * 128 + k4 * 4];
            s4.x += wv.x * smB[(k4 * 4 + 0) * HP + p];
            s4.y += wv.y * smB[(k4 * 4 + 1) * HP + p];
            s4.z += wv.z * smB[(k4 * 4 + 2) * HP + p];
            s4.w += wv.w * smB[(k4 * 4 + 3) * HP + p];
        }
        out[((size_t)(p0 + p)) * 6 + o] = (s4.x + s4.y) + (s4.z + s4.w);
    }
}

extern "C" void kernel_launch(void* const* d_in, const int* in_sizes, int n_in,
                              void* d_out, int out_size, void* d_ws, size_t ws_size,
                              hipStream_t stream) {
    const float* points = (const float*)d_in[0];
    const float* label  = (const float*)d_in[1];
    const float* w1  = (const float*)d_in[2];
    const float* s1  = (const float*)d_in[3];
    const float* b1  = (const float*)d_in[4];
    const float* w2  = (const float*)d_in[5];
    const float* s2  = (const float*)d_in[6];
    const float* b2  = (const float*)d_in[7];
    const float* w3  = (const float*)d_in[8];
    const float* s3  = (const float*)d_in[9];
    const float* b3  = (const float*)d_in[10];
    const float* w4  = (const float*)d_in[11];
    const float* s4  = (const float*)d_in[12];
    const float* b4  = (const float*)d_in[13];
    const float* w5  = (const float*)d_in[14];
    const float* s5  = (const float*)d_in[15];
    const float* b5  = (const float*)d_in[16];
    const float* w6  = (const float*)d_in[17];
    const float* s6  = (const float*)d_in[18];
    const float* b6  = (const float*)d_in[19];
    const float* w7  = (const float*)d_in[20];
    const float* s7  = (const float*)d_in[21];
    const float* b7  = (const float*)d_in[22];
    const float* wp1 = (const float*)d_in[23];
    const float* sp1 = (const float*)d_in[24];
    const float* bp1 = (const float*)d_in[25];
    const float* wp2 = (const float*)d_in[26];
    const float* sp2 = (const float*)d_in[27];
    const float* bp2 = (const float*)d_in[28];
    const float* wp3 = (const float*)d_in[29];
    const float* sp3 = (const float*)d_in[30];
    const float* bp3 = (const float*)d_in[31];
    const float* wp4 = (const float*)d_in[32];

    float* ws = (float*)d_ws;
    size_t off = 0;
    auto alloc = [&](size_t nf) { float* p = ws + off; off += nf; return p; };
    float* out1t = alloc((size_t)BATCH * NPTS * 64);
    float* out2t = alloc((size_t)BATCH * NPTS * 64);
    float* out3t = alloc((size_t)BATCH * NPTS * 64);
    float* sqb   = alloc((size_t)BATCH * NPTS);
    float* out4m = alloc((size_t)BATCH * 1024);
    float* catv  = alloc((size_t)BATCH * 64);
    float* gb    = alloc((size_t)BATCH * 256);
    float* w6t   = alloc((size_t)192 * 1024);
    float* part  = alloc((size_t)512 * 1024);
    int* idx1 = (int*)alloc((size_t)BATCH * NPTS * KNN);
    int* idx2 = (int*)alloc((size_t)BATCH * NPTS * KNN);
    int* idx3 = (int*)alloc((size_t)BATCH * NPTS * KNN);

    const int BN = BATCH * NPTS;
    const int sqBlocks = (BN + 255) / 256;

    // stage 1
    sq_kernel<3><<<sqBlocks, 256, 0, stream>>>(points, sqb);
    knn3_kernel<<<BN, 64, 0, stream>>>(points, sqb, idx1);
    edgeconv1_kernel<<<BN, 64, 0, stream>>>(points, idx1, w1, s1, b1, w2, s2, b2, out1t);

    // stage 2
    sq64_kernel<<<sqBlocks, 256, 0, stream>>>(out1t, sqb);
    knn64_kernel<<<BN / 8, 256, 0, stream>>>(out1t, sqb, idx2);
    edgeconv2_kernel<<<BN, 64, 0, stream>>>(out1t, idx2, w3, s3, b3, w4, s4, b4, out2t);

    // stage 3
    sq64_kernel<<<sqBlocks, 256, 0, stream>>>(out2t, sqb);
    knn64_kernel<<<BN / 8, 256, 0, stream>>>(out2t, sqb, idx3);
    edgeconv3_kernel<<<BN, 64, 0, stream>>>(out2t, idx3, w5, s5, b5, out3t);

    // global branches
    catvet_kernel<<<BATCH, 64, 0, stream>>>(label, w7, s7, b7, catv);
    w6t_kernel<<<(192 * 1024 + 255) / 256, 256, 0, stream>>>(w6, w6t);
    out4max_kernel<<<512, 256, 0, stream>>>(out1t, out2t, out3t, w6t, part);
    out4reduce_kernel<<<BATCH * 1024 / 256, 256, 0, stream>>>(part, s6, b6, out4m);
    gbias_kernel<<<BATCH, 256, 0, stream>>>(out4m, catv, wp1, gb);

    // head
    head_kernel<<<BN / HP, 256, 0, stream>>>(out1t, out2t, out3t, gb,
                                             wp1, sp1, bp1, wp2, sp2, bp2, wp3, sp3, bp3,
                                             wp4, (float*)d_out);
}

// Round 9
// 1081.802 us; speedup vs baseline: 2.0789x; 1.0319x over previous
//
#include <hip/hip_runtime.h>
#include <float.h>

#define NEG 0.2f
constexpr int BATCH = 8;
constexpr int NPTS  = 2048;
constexpr int KNN   = 10;
constexpr int KP1   = 11;

__device__ __forceinline__ float lrelu(float x) { return x > 0.f ? x : NEG * x; }

// ordered-u64 key: (monotone uint of d2) << 32 | idx  => u64 '<' == (d2 asc, idx asc)
__device__ __forceinline__ unsigned long long dkey(float d, int m) {
    unsigned u = __float_as_uint(d);
    u ^= (unsigned)((int)u >> 31) | 0x80000000u;
    return ((unsigned long long)u << 32) | (unsigned)m;
}

// ---------------- squared-norm per point ----------------
template<int D>
__global__ void sq_kernel(const float* __restrict__ xt, float* __restrict__ sq) {
    int i = blockIdx.x * 256 + threadIdx.x;
    if (i >= BATCH * NPTS) return;
    const float* p = xt + (size_t)i * D;
    float s = 0.f;
    #pragma unroll
    for (int d = 0; d < D; ++d) s += p[d] * p[d];
    sq[i] = s;
}

__global__ void sq64_kernel(const float* __restrict__ xt, float* __restrict__ sq) {
    int i = blockIdx.x * 256 + threadIdx.x;
    if (i >= BATCH * NPTS) return;
    const float4* p = (const float4*)(xt + (size_t)i * 64);
    float4 s4 = {0.f, 0.f, 0.f, 0.f};
    #pragma unroll
    for (int d = 0; d < 16; ++d) {
        float4 v = p[d];
        s4.x += v.x * v.x; s4.y += v.y * v.y; s4.z += v.z * v.z; s4.w += v.w * v.w;
    }
    sq[i] = (s4.x + s4.y) + (s4.z + s4.w);
}

// ---------------- kNN D=3: one WAVE per (b,n); register top-11 + shuffle extraction ----------------
__global__ __launch_bounds__(64) void knn3_kernel(const float* __restrict__ xt,
                                                  const float* __restrict__ sq,
                                                  int* __restrict__ idx_out) {
    const int bn = blockIdx.x;
    const int b  = bn >> 11;           // NPTS = 2048
    const int l  = threadIdx.x;

    const float qx = xt[(size_t)bn * 3 + 0];
    const float qy = xt[(size_t)bn * 3 + 1];
    const float qz = xt[(size_t)bn * 3 + 2];
    const float sqn = sq[bn];
    const float* xb  = xt + (size_t)b * NPTS * 3;
    const float* sqb_ = sq + (size_t)b * NPTS;

    unsigned long long lk[KP1];
    #pragma unroll
    for (int j = 0; j < KP1; ++j) lk[j] = ~0ULL;

    for (int m = l; m < NPTS; m += 64) {
        float dot = 0.f;
        dot += qx * xb[m * 3 + 0];
        dot += qy * xb[m * 3 + 1];
        dot += qz * xb[m * 3 + 2];
        float cd = sqn + sqb_[m] - 2.f * dot;
        unsigned long long key = dkey(cd, m);
        if (key < lk[KP1 - 1]) {
            #pragma unroll
            for (int j = 0; j < KP1; ++j) {
                bool better = key < lk[j];
                unsigned long long tk = lk[j];
                if (better) { lk[j] = key; key = tk; }
            }
        }
    }

    // width-64 min-extraction: 11 ascending unique keys == merged top-11
    #pragma unroll
    for (int k = 0; k < KP1; ++k) {
        unsigned long long mk = lk[0];
        #pragma unroll
        for (int s = 32; s >= 1; s >>= 1) {
            unsigned long long o = __shfl_xor(mk, s, 64);
            mk = (o < mk) ? o : mk;
        }
        if (k >= 1 && l == k - 1)
            idx_out[(size_t)bn * KNN + (k - 1)] = (int)(unsigned)mk;
        if (lk[0] == mk) {   // unique winner pops (static shift)
            #pragma unroll
            for (int j = 0; j < KP1 - 1; ++j) lk[j] = lk[j + 1];
            lk[KP1 - 1] = ~0ULL;
        }
    }
}

// ---------------- kNN D=64: dim-split halves + double-buffered tile ----------------
// Wave w handles queries qA=bn0+2w (lanes 0-31) and qB=qA+1 (lanes 32-63).
// Lane l: candidate l&31, dim-half h=l>>5; computes PARTIAL dots for BOTH queries
// (8 unique-f4 reads/cand, LDS at 1KB/8cyc floor), halves recombined via shfl_xor(32).
// Double-buffered tile: 1 barrier/iter, next tile prefetched to regs during compute.
__global__ __launch_bounds__(256) void knn64_kernel(const float* __restrict__ xt,
                                                    const float* __restrict__ sq,
                                                    int* __restrict__ idx_out) {
    const int t  = threadIdx.x;
    const int qg = t >> 5;   // query slot (0..7): this lane-group's output query
    const int lc = t & 31;   // candidate lane
    const int h  = qg & 1;   // dim half within wave
    const int w  = t >> 6;   // wave id (0..3)
    const int bn0 = blockIdx.x * 8;
    const int bn  = bn0 + qg;
    const int qA  = bn0 + 2 * w;
    const int qB  = qA + 1;
    const int b   = bn >> 11;          // NPTS = 2048
    const float* xb = xt + (size_t)b * NPTS * 64;

    __shared__ __align__(16) float4 tile4[2][32][16];   // 16 KB double buffer

    // own half (dims [h*32, h*32+32)) of BOTH wave queries
    float4 xqa[8], xqb[8];
    {
        const float4* pa = (const float4*)(xt + (size_t)qA * 64 + h * 32);
        const float4* pb = (const float4*)(xt + (size_t)qB * 64 + h * 32);
        #pragma unroll
        for (int i = 0; i < 8; ++i) { xqa[i] = pa[i]; xqb[i] = pb[i]; }
    }
    const float sqn = sq[bn];
    const float* sqb_ = sq + b * NPTS;

    unsigned long long lk[KP1];
    #pragma unroll
    for (int j = 0; j < KP1; ++j) lk[j] = ~0ULL;

    const int ci  = t >> 3;   // staging: candidate within tile (0..31)
    const int sub = t & 7;    // staging: 8-dim slice (2 f4 slots)

    // prologue: stage tile 0 into buf 0
    {
        const float4* src = (const float4*)(xb + (size_t)ci * 64 + sub * 8);
        float4 u0 = src[0], u1 = src[1];
        tile4[0][ci][(2 * sub)     ^ (ci & 15)] = u0;
        tile4[0][ci][(2 * sub + 1) ^ (ci & 15)] = u1;
    }
    __syncthreads();

    int cur = 0;
    for (int t0 = 0; t0 < NPTS; t0 += 32) {
        // prefetch next tile into regs (latency hidden under compute)
        float4 n0, n1;
        const bool more = (t0 + 32 < NPTS);
        if (more) {
            const float4* src = (const float4*)(xb + (size_t)(t0 + 32 + ci) * 64 + sub * 8);
            n0 = src[0]; n1 = src[1];
        }

        // partial dots (own half) for both wave queries
        float a0 = 0.f, a1 = 0.f, a2 = 0.f, a3 = 0.f;
        float c0 = 0.f, c1 = 0.f, c2 = 0.f, c3 = 0.f;
        #pragma unroll
        for (int i = 0; i < 8; ++i) {
            float4 v = tile4[cur][lc][(h * 8 + i) ^ (lc & 15)];
            a0 += xqa[i].x * v.x; a1 += xqa[i].y * v.y;
            a2 += xqa[i].z * v.z; a3 += xqa[i].w * v.w;
            c0 += xqb[i].x * v.x; c1 += xqb[i].y * v.y;
            c2 += xqb[i].z * v.z; c3 += xqb[i].w * v.w;
        }
        float pA = (a0 + a1) + (a2 + a3);
        float pB = (c0 + c1) + (c2 + c3);
        float oA = __shfl_xor(pA, 32, 64);
        float oB = __shfl_xor(pB, 32, 64);
        // full dot in h0+h1 order for the lane-group's own query
        float dot = (h == 0) ? (pA + oA) : (oB + pB);

        const int m = t0 + lc;
        float cd = sqn + sqb_[m] - 2.f * dot;
        unsigned long long key = dkey(cd, m);
        if (key < lk[KP1 - 1]) {
            #pragma unroll
            for (int j = 0; j < KP1; ++j) {
                bool better = key < lk[j];
                unsigned long long tk = lk[j];
                if (better) { lk[j] = key; key = tk; }
            }
        }

        // write next tile to the other buffer; single barrier flips roles
        if (more) {
            tile4[cur ^ 1][ci][(2 * sub)     ^ (ci & 15)] = n0;
            tile4[cur ^ 1][ci][(2 * sub + 1) ^ (ci & 15)] = n1;
        }
        __syncthreads();
        cur ^= 1;
    }

    // width-32 min-extraction within each lane-group (keys unique -> one pop/iter)
    #pragma unroll
    for (int k = 0; k < KP1; ++k) {
        unsigned long long mk = lk[0];
        #pragma unroll
        for (int s = 16; s >= 1; s >>= 1) {
            unsigned long long o = __shfl_xor(mk, s, 32);
            mk = (o < mk) ? o : mk;
        }
        if (k >= 1 && lc == k - 1)
            idx_out[(size_t)bn * KNN + (k - 1)] = (int)(unsigned)mk;
        if (lk[0] == mk) {
            #pragma unroll
            for (int j = 0; j < KP1 - 1; ++j) lk[j] = lk[j + 1];
            lk[KP1 - 1] = ~0ULL;
        }
    }
}

// ---------------- edge conv stage 1: points(3) -> 64 -> 64 -> max_k ----------------
__global__ __launch_bounds__(64) void edgeconv1_kernel(
    const float* __restrict__ pts, const int* __restrict__ idx,
    const float* __restrict__ w1, const float* __restrict__ s1, const float* __restrict__ b1,
    const float* __restrict__ w2, const float* __restrict__ s2, const float* __restrict__ b2,
    float* __restrict__ outt) {
    const int bn = blockIdx.x;
    const int b  = bn / NPTS;
    const int c  = threadIdx.x;

    const float cx = pts[bn * 3 + 0], cy = pts[bn * 3 + 1], cz = pts[bn * 3 + 2];

    float w1r[6];
    #pragma unroll
    for (int i = 0; i < 6; ++i) w1r[i] = w1[c * 6 + i];
    const float s1c = s1[c], b1c = b1[c], s2c = s2[c], b2c = b2[c];

    __shared__ float h1all[KNN][64];
    #pragma unroll
    for (int k = 0; k < KNN; ++k) {
        const int m = idx[bn * KNN + k];
        const float* f = pts + ((size_t)b * NPTS + m) * 3;
        const float e0 = f[0] - cx, e1 = f[1] - cy, e2 = f[2] - cz;
        float a = w1r[0] * e0 + w1r[1] * e1 + w1r[2] * e2
                + w1r[3] * cx + w1r[4] * cy + w1r[5] * cz;
        h1all[k][c] = lrelu(a * s1c + b1c);
    }
    __syncthreads();

    float a2[KNN];
    #pragma unroll
    for (int k = 0; k < KNN; ++k) a2[k] = 0.f;
    for (int j4 = 0; j4 < 16; ++j4) {
        float4 wv = *(const float4*)&w2[c * 64 + j4 * 4];
        #pragma unroll
        for (int k = 0; k < KNN; ++k) {
            float4 h4 = *(const float4*)&h1all[k][j4 * 4];
            a2[k] += wv.x * h4.x + wv.y * h4.y + wv.z * h4.z + wv.w * h4.w;
        }
    }
    float mx = -FLT_MAX;
    #pragma unroll
    for (int k = 0; k < KNN; ++k) mx = fmaxf(mx, lrelu(a2[k] * s2c + b2c));
    outt[(size_t)bn * 64 + c] = mx;
}

// ---------------- edge conv stage 2: feat64 -> (128) -> 64 -> 64 -> max_k ----------------
__global__ __launch_bounds__(64) void edgeconv2_kernel(
    const float* __restrict__ xin, const int* __restrict__ idx,
    const float* __restrict__ w3, const float* __restrict__ s3, const float* __restrict__ b3,
    const float* __restrict__ w4, const float* __restrict__ s4, const float* __restrict__ b4,
    float* __restrict__ outt) {
    const int bn = blockIdx.x;
    const int b  = bn / NPTS;
    const int c  = threadIdx.x;

    __shared__ float cen[64];
    __shared__ float fea[KNN][64];
    __shared__ float h1all[KNN][64];
    cen[c] = xin[(size_t)bn * 64 + c];
    #pragma unroll
    for (int k = 0; k < KNN; ++k) {
        const int m = idx[bn * KNN + k];
        fea[k][c] = xin[((size_t)b * NPTS + m) * 64 + c];
    }
    __syncthreads();

    float a[KNN];
    #pragma unroll
    for (int k = 0; k < KNN; ++k) a[k] = 0.f;
    float4 ab = {0.f, 0.f, 0.f, 0.f};
    for (int j4 = 0; j4 < 16; ++j4) {
        float4 wa = *(const float4*)&w3[c * 128 + j4 * 4];
        float4 wb = *(const float4*)&w3[c * 128 + 64 + j4 * 4];
        float4 c4 = *(const float4*)&cen[j4 * 4];
        ab.x += (wb.x - wa.x) * c4.x; ab.y += (wb.y - wa.y) * c4.y;
        ab.z += (wb.z - wa.z) * c4.z; ab.w += (wb.w - wa.w) * c4.w;
        #pragma unroll
        for (int k = 0; k < KNN; ++k) {
            float4 f4 = *(const float4*)&fea[k][j4 * 4];
            a[k] += wa.x * f4.x + wa.y * f4.y + wa.z * f4.z + wa.w * f4.w;
        }
    }
    const float abase = (ab.x + ab.y) + (ab.z + ab.w);
    const float s3c = s3[c], b3c = b3[c], s4c = s4[c], b4c = b4[c];
    #pragma unroll
    for (int k = 0; k < KNN; ++k) h1all[k][c] = lrelu((a[k] + abase) * s3c + b3c);
    __syncthreads();

    float a2[KNN];
    #pragma unroll
    for (int k = 0; k < KNN; ++k) a2[k] = 0.f;
    for (int j4 = 0; j4 < 16; ++j4) {
        float4 wv = *(const float4*)&w4[c * 64 + j4 * 4];
        #pragma unroll
        for (int k = 0; k < KNN; ++k) {
            float4 h4 = *(const float4*)&h1all[k][j4 * 4];
            a2[k] += wv.x * h4.x + wv.y * h4.y + wv.z * h4.z + wv.w * h4.w;
        }
    }
    float mx = -FLT_MAX;
    #pragma unroll
    for (int k = 0; k < KNN; ++k) mx = fmaxf(mx, lrelu(a2[k] * s4c + b4c));
    outt[(size_t)bn * 64 + c] = mx;
}

// ---------------- edge conv stage 3: feat64 -> (128) -> 64 -> max_k ----------------
__global__ __launch_bounds__(64) void edgeconv3_kernel(
    const float* __restrict__ xin, const int* __restrict__ idx,
    const float* __restrict__ w5, const float* __restrict__ s5, const float* __restrict__ b5,
    float* __restrict__ outt) {
    const int bn = blockIdx.x;
    const int b  = bn / NPTS;
    const int c  = threadIdx.x;

    __shared__ float cen[64];
    __shared__ float fea[KNN][64];
    cen[c] = xin[(size_t)bn * 64 + c];
    #pragma unroll
    for (int k = 0; k < KNN; ++k) {
        const int m = idx[bn * KNN + k];
        fea[k][c] = xin[((size_t)b * NPTS + m) * 64 + c];
    }
    __syncthreads();

    float a[KNN];
    #pragma unroll
    for (int k = 0; k < KNN; ++k) a[k] = 0.f;
    float4 ab = {0.f, 0.f, 0.f, 0.f};
    for (int j4 = 0; j4 < 16; ++j4) {
        float4 wa = *(const float4*)&w5[c * 128 + j4 * 4];
        float4 wb = *(const float4*)&w5[c * 128 + 64 + j4 * 4];
        float4 c4 = *(const float4*)&cen[j4 * 4];
        ab.x += (wb.x - wa.x) * c4.x; ab.y += (wb.y - wa.y) * c4.y;
        ab.z += (wb.z - wa.z) * c4.z; ab.w += (wb.w - wa.w) * c4.w;
        #pragma unroll
        for (int k = 0; k < KNN; ++k) {
            float4 f4 = *(const float4*)&fea[k][j4 * 4];
            a[k] += wa.x * f4.x + wa.y * f4.y + wa.z * f4.z + wa.w * f4.w;
        }
    }
    const float abase = (ab.x + ab.y) + (ab.z + ab.w);
    const float s5c = s5[c], b5c = b5[c];
    float mx = -FLT_MAX;
    #pragma unroll
    for (int k = 0; k < KNN; ++k) mx = fmaxf(mx, lrelu((a[k] + abase) * s5c + b5c));
    outt[(size_t)bn * 64 + c] = mx;
}

// ---------------- label branch: (16) -> 64 ----------------
__global__ __launch_bounds__(64) void catvet_kernel(
    const float* __restrict__ label,
    const float* __restrict__ w7, const float* __restrict__ s7, const float* __restrict__ b7,
    float* __restrict__ catv) {
    const int b = blockIdx.x, c = threadIdx.x;
    float a = 0.f;
    #pragma unroll
    for (int i = 0; i < 16; ++i) a += w7[c * 16 + i] * label[b * 16 + i];
    catv[b * 64 + c] = lrelu(a * s7[c] + b7[c]);
}

// ---------------- w6 transpose: w6t[k][c] = w6[c][k] (one-time, 768 KB) ----------------
__global__ void w6t_kernel(const float* __restrict__ w6, float* __restrict__ w6t) {
    int i = blockIdx.x * 256 + threadIdx.x;
    if (i >= 192 * 1024) return;
    int k = i >> 10, c = i & 1023;
    w6t[i] = w6[c * 192 + k];
}

// ---------------- global feature GEMM: raw max_n( w6 . x[n] ) per channel ----------------
constexpr int OPTS = 32;
__global__ __launch_bounds__(256) void out4max_kernel(
    const float* __restrict__ out1t, const float* __restrict__ out2t, const float* __restrict__ out3t,
    const float* __restrict__ w6t, float* __restrict__ partial) {
    const int blk = blockIdx.x;
    const int b   = blk >> 6;
    const int nt  = blk & 63;
    const int t   = threadIdx.x;

    __shared__ float xs[192 * OPTS];   // [k][p], 24 KB; reads are all-lane broadcasts
    for (int idx = t; idx < 192 * OPTS; idx += 256) {
        int p = idx / 192, r = idx - p * 192;
        const size_t gp = (size_t)b * NPTS + nt * OPTS + p;
        float val;
        if (r < 64)       val = out1t[gp * 64 + r];
        else if (r < 128) val = out2t[gp * 64 + (r - 64)];
        else              val = out3t[gp * 64 + (r - 128)];
        xs[r * OPTS + p] = val;
    }
    __syncthreads();

    float mx0 = -FLT_MAX, mx1 = -FLT_MAX, mx2 = -FLT_MAX, mx3 = -FLT_MAX;
    #pragma unroll
    for (int pg = 0; pg < OPTS / 16; ++pg) {
        float acc0[16], acc1[16], acc2[16], acc3[16];
        #pragma unroll
        for (int p = 0; p < 16; ++p) { acc0[p] = 0.f; acc1[p] = 0.f; acc2[p] = 0.f; acc3[p] = 0.f; }
        #pragma unroll 2
        for (int k = 0; k < 192; ++k) {
            float4 wv = *(const float4*)&w6t[(size_t)k * 1024 + t * 4];
            const float4* xr4 = (const float4*)&xs[k * OPTS + pg * 16];
            #pragma unroll
            for (int p4 = 0; p4 < 4; ++p4) {
                float4 xv = xr4[p4];
                acc0[p4 * 4 + 0] += wv.x * xv.x; acc0[p4 * 4 + 1] += wv.x * xv.y;
                acc0[p4 * 4 + 2] += wv.x * xv.z; acc0[p4 * 4 + 3] += wv.x * xv.w;
                acc1[p4 * 4 + 0] += wv.y * xv.x; acc1[p4 * 4 + 1] += wv.y * xv.y;
                acc1[p4 * 4 + 2] += wv.y * xv.z; acc1[p4 * 4 + 3] += wv.y * xv.w;
                acc2[p4 * 4 + 0] += wv.z * xv.x; acc2[p4 * 4 + 1] += wv.z * xv.y;
                acc2[p4 * 4 + 2] += wv.z * xv.z; acc2[p4 * 4 + 3] += wv.z * xv.w;
                acc3[p4 * 4 + 0] += wv.w * xv.x; acc3[p4 * 4 + 1] += wv.w * xv.y;
                acc3[p4 * 4 + 2] += wv.w * xv.z; acc3[p4 * 4 + 3] += wv.w * xv.w;
            }
        }
        #pragma unroll
        for (int p = 0; p < 16; ++p) {
            mx0 = fmaxf(mx0, acc0[p]); mx1 = fmaxf(mx1, acc1[p]);
            mx2 = fmaxf(mx2, acc2[p]); mx3 = fmaxf(mx3, acc3[p]);
        }
    }
    float4 o = {mx0, mx1, mx2, mx3};
    *(float4*)&partial[(size_t)blk * 1024 + t * 4] = o;
}

__global__ __launch_bounds__(256) void out4reduce_kernel(
    const float* __restrict__ partial,
    const float* __restrict__ s6, const float* __restrict__ b6,
    float* __restrict__ out4m) {
    const int i = blockIdx.x * 256 + threadIdx.x;  // 8192 = 8 * 1024
    const int b = i >> 10, c = i & 1023;
    float m = -FLT_MAX;
    for (int nt = 0; nt < 64; ++nt)
        m = fmaxf(m, partial[((size_t)b * 64 + nt) * 1024 + c]);
    out4m[i] = lrelu(m * s6[c] + b6[c]);
}

// ---------------- per-batch head bias: g[b][o] = wp1[o,192:1280] . [out4m;catv] ----------------
__global__ __launch_bounds__(256) void gbias_kernel(
    const float* __restrict__ out4m, const float* __restrict__ catv,
    const float* __restrict__ wp1, float* __restrict__ g) {
    const int b = blockIdx.x, t = threadIdx.x;
    __shared__ float v[1088];
    for (int i = t; i < 1088; i += 256)
        v[i] = (i < 1024) ? out4m[(size_t)b * 1024 + i] : catv[(size_t)b * 64 + (i - 1024)];
    __syncthreads();
    const float* w = wp1 + (size_t)t * 1280 + 192;
    float4 s4 = {0.f, 0.f, 0.f, 0.f};
    for (int i = 0; i < 272; ++i) {
        float4 wv = *(const float4*)&w[i * 4];
        float4 vv = *(const float4*)&v[i * 4];
        s4.x += wv.x * vv.x; s4.y += wv.y * vv.y; s4.z += wv.z * vv.z; s4.w += wv.w * vv.w;
    }
    g[(size_t)b * 256 + t] = (s4.x + s4.y) + (s4.z + s4.w);
}

// ---------------- per-point head (tiled GEMM): 192 -> 256 -> 256 -> 128 -> 6 ----------------
constexpr int HP = 16;   // points per block
constexpr int KC = 16;   // k-chunk

__global__ __launch_bounds__(256) void head_kernel(
    const float* __restrict__ out1t, const float* __restrict__ out2t, const float* __restrict__ out3t,
    const float* __restrict__ g,
    const float* __restrict__ wp1, const float* __restrict__ sp1, const float* __restrict__ bp1,
    const float* __restrict__ wp2, const float* __restrict__ sp2, const float* __restrict__ bp2,
    const float* __restrict__ wp3, const float* __restrict__ sp3, const float* __restrict__ bp3,
    const float* __restrict__ wp4, float* __restrict__ out) {
    const int p0 = blockIdx.x * HP;
    const int b  = p0 >> 11;
    const int t  = threadIdx.x;

    __shared__ float smA[4096];      // xs[192][16] then t2s[256][16]
    __shared__ float smB[4096];      // t1s[256][16] then t3s[128][16]
    __shared__ float smW[KC * 256];  // weight chunk, k-major

    for (int e = t; e < 192 * HP; e += 256) {
        int p = e / 192, k = e - p * 192;
        float val;
        if (k < 64)       val = out1t[((size_t)(p0 + p)) * 64 + k];
        else if (k < 128) val = out2t[((size_t)(p0 + p)) * 64 + (k - 64)];
        else              val = out3t[((size_t)(p0 + p)) * 64 + (k - 128)];
        smA[k * HP + p] = val;
    }

    const int og = t & 31;   // 8 outs each
    const int pg = t >> 5;   // 2 points each

    // ---- layer 1: 192 -> 256, acc init = per-batch g ----
    float acc[2][8];
    #pragma unroll
    for (int i = 0; i < 8; ++i) {
        float gv = g[(size_t)b * 256 + og * 8 + i];
        acc[0][i] = gv; acc[1][i] = gv;
    }
    for (int kc = 0; kc < 192 / KC; ++kc) {
        __syncthreads();
        #pragma unroll
        for (int it = 0; it < KC; ++it)
            smW[it * 256 + t] = wp1[(size_t)t * 1280 + kc * KC + it];
        __syncthreads();
        #pragma unroll 4
        for (int kk = 0; kk < KC; ++kk) {
            int k = kc * KC + kk;
            float2 xv = *(const float2*)&smA[k * HP + pg * 2];
            float4 w0 = *(const float4*)&smW[kk * 256 + og * 8];
            float4 w1v = *(const float4*)&smW[kk * 256 + og * 8 + 4];
            float wv[8] = {w0.x, w0.y, w0.z, w0.w, w1v.x, w1v.y, w1v.z, w1v.w};
            #pragma unroll
            for (int i = 0; i < 8; ++i) {
                acc[0][i] += xv.x * wv[i];
                acc[1][i] += xv.y * wv[i];
            }
        }
    }
    #pragma unroll
    for (int i = 0; i < 8; ++i) {
        int o = og * 8 + i;
        float sc = sp1[o], bc = bp1[o];
        smB[o * HP + pg * 2 + 0] = lrelu(acc[0][i] * sc + bc);
        smB[o * HP + pg * 2 + 1] = lrelu(acc[1][i] * sc + bc);
    }

    // ---- layer 2: 256 -> 256 ----
    float acc2[2][8];
    #pragma unroll
    for (int i = 0; i < 8; ++i) { acc2[0][i] = 0.f; acc2[1][i] = 0.f; }
    for (int kc = 0; kc < 256 / KC; ++kc) {
        __syncthreads();
        #pragma unroll
        for (int it = 0; it < KC; ++it)
            smW[it * 256 + t] = wp2[(size_t)t * 256 + kc * KC + it];
        __syncthreads();
        #pragma unroll 4
        for (int kk = 0; kk < KC; ++kk) {
            int k = kc * KC + kk;
            float2 xv = *(const float2*)&smB[k * HP + pg * 2];
            float4 w0 = *(const float4*)&smW[kk * 256 + og * 8];
            float4 w1v = *(const float4*)&smW[kk * 256 + og * 8 + 4];
            float wv[8] = {w0.x, w0.y, w0.z, w0.w, w1v.x, w1v.y, w1v.z, w1v.w};
            #pragma unroll
            for (int i = 0; i < 8; ++i) {
                acc2[0][i] += xv.x * wv[i];
                acc2[1][i] += xv.y * wv[i];
            }
        }
    }
    __syncthreads();
    #pragma unroll
    for (int i = 0; i < 8; ++i) {
        int o = og * 8 + i;
        float sc = sp2[o], bc = bp2[o];
        smA[o * HP + pg * 2 + 0] = lrelu(acc2[0][i] * sc + bc);
        smA[o * HP + pg * 2 + 1] = lrelu(acc2[1][i] * sc + bc);
    }

    // ---- layer 3: 256 -> 128 ----
    const int og3 = t & 15;
    const int p3  = t >> 4;
    float acc3[8];
    #pragma unroll
    for (int i = 0; i < 8; ++i) acc3[i] = 0.f;
    for (int kc = 0; kc < 256 / KC; ++kc) {
        __syncthreads();
        for (int e = t; e < KC * 128; e += 256) {
            int kk = e >> 7, o = e & 127;
            smW[kk * 128 + o] = wp3[(size_t)o * 256 + kc * KC + kk];
        }
        __syncthreads();
        #pragma unroll 4
        for (int kk = 0; kk < KC; ++kk) {
            int k = kc * KC + kk;
            float xv = smA[k * HP + p3];
            float4 w0 = *(const float4*)&smW[kk * 128 + og3 * 8];
            float4 w1v = *(const float4*)&smW[kk * 128 + og3 * 8 + 4];
            float wv[8] = {w0.x, w0.y, w0.z, w0.w, w1v.x, w1v.y, w1v.z, w1v.w};
            #pragma unroll
            for (int i = 0; i < 8; ++i) acc3[i] += xv * wv[i];
        }
    }
    __syncthreads();
    #pragma unroll
    for (int i = 0; i < 8; ++i) {
        int o = og3 * 8 + i;
        float sc = sp3[o], bc = bp3[o];
        smB[o * HP + p3] = lrelu(acc3[i] * sc + bc);
    }
    __syncthreads();

    // ---- layer 4: 128 -> 6 ----
    if (t < HP * 6) {
        int p = t / 6, o = t - p * 6;
        float4 s4 = {0.f, 0.f, 0.f, 0.f};
        for (int k4 = 0; k4 < 32; ++k4) {
            float4 wv = *(const float4*)&wp4[o * 128 + k4 * 4];
            s4.x += wv.x * smB[(k4 * 4 + 0) * HP + p];
            s4.y += wv.y * smB[(k4 * 4 + 1) * HP + p];
            s4.z += wv.z * smB[(k4 * 4 + 2) * HP + p];
            s4.w += wv.w * smB[(k4 * 4 + 3) * HP + p];
        }
        out[((size_t)(p0 + p)) * 6 + o] = (s4.x + s4.y) + (s4.z + s4.w);
    }
}

extern "C" void kernel_launch(void* const* d_in, const int* in_sizes, int n_in,
                              void* d_out, int out_size, void* d_ws, size_t ws_size,
                              hipStream_t stream) {
    const float* points = (const float*)d_in[0];
    const float* label  = (const float*)d_in[1];
    const float* w1  = (const float*)d_in[2];
    const float* s1  = (const float*)d_in[3];
    const float* b1  = (const float*)d_in[4];
    const float* w2  = (const float*)d_in[5];
    const float* s2  = (const float*)d_in[6];
    const float* b2  = (const float*)d_in[7];
    const float* w3  = (const float*)d_in[8];
    const float* s3  = (const float*)d_in[9];
    const float* b3  = (const float*)d_in[10];
    const float* w4  = (const float*)d_in[11];
    const float* s4  = (const float*)d_in[12];
    const float* b4  = (const float*)d_in[13];
    const float* w5  = (const float*)d_in[14];
    const float* s5  = (const float*)d_in[15];
    const float* b5  = (const float*)d_in[16];
    const float* w6  = (const float*)d_in[17];
    const float* s6  = (const float*)d_in[18];
    const float* b6  = (const float*)d_in[19];
    const float* w7  = (const float*)d_in[20];
    const float* s7  = (const float*)d_in[21];
    const float* b7  = (const float*)d_in[22];
    const float* wp1 = (const float*)d_in[23];
    const float* sp1 = (const float*)d_in[24];
    const float* bp1 = (const float*)d_in[25];
    const float* wp2 = (const float*)d_in[26];
    const float* sp2 = (const float*)d_in[27];
    const float* bp2 = (const float*)d_in[28];
    const float* wp3 = (const float*)d_in[29];
    const float* sp3 = (const float*)d_in[30];
    const float* bp3 = (const float*)d_in[31];
    const float* wp4 = (const float*)d_in[32];

    float* ws = (float*)d_ws;
    size_t off = 0;
    auto alloc = [&](size_t nf) { float* p = ws + off; off += nf; return p; };
    float* out1t = alloc((size_t)BATCH * NPTS * 64);
    float* out2t = alloc((size_t)BATCH * NPTS * 64);
    float* out3t = alloc((size_t)BATCH * NPTS * 64);
    float* sqb   = alloc((size_t)BATCH * NPTS);
    float* out4m = alloc((size_t)BATCH * 1024);
    float* catv  = alloc((size_t)BATCH * 64);
    float* gb    = alloc((size_t)BATCH * 256);
    float* w6t   = alloc((size_t)192 * 1024);
    float* part  = alloc((size_t)512 * 1024);
    int* idx1 = (int*)alloc((size_t)BATCH * NPTS * KNN);
    int* idx2 = (int*)alloc((size_t)BATCH * NPTS * KNN);
    int* idx3 = (int*)alloc((size_t)BATCH * NPTS * KNN);

    const int BN = BATCH * NPTS;
    const int sqBlocks = (BN + 255) / 256;

    // stage 1
    sq_kernel<3><<<sqBlocks, 256, 0, stream>>>(points, sqb);
    knn3_kernel<<<BN, 64, 0, stream>>>(points, sqb, idx1);
    edgeconv1_kernel<<<BN, 64, 0, stream>>>(points, idx1, w1, s1, b1, w2, s2, b2, out1t);

    // stage 2
    sq64_kernel<<<sqBlocks, 256, 0, stream>>>(out1t, sqb);
    knn64_kernel<<<BN / 8, 256, 0, stream>>>(out1t, sqb, idx2);
    edgeconv2_kernel<<<BN, 64, 0, stream>>>(out1t, idx2, w3, s3, b3, w4, s4, b4, out2t);

    // stage 3
    sq64_kernel<<<sqBlocks, 256, 0, stream>>>(out2t, sqb);
    knn64_kernel<<<BN / 8, 256, 0, stream>>>(out2t, sqb, idx3);
    edgeconv3_kernel<<<BN, 64, 0, stream>>>(out2t, idx3, w5, s5, b5, out3t);

    // global branches
    catvet_kernel<<<BATCH, 64, 0, stream>>>(label, w7, s7, b7, catv);
    w6t_kernel<<<(192 * 1024 + 255) / 256, 256, 0, stream>>>(w6, w6t);
    out4max_kernel<<<512, 256, 0, stream>>>(out1t, out2t, out3t, w6t, part);
    out4reduce_kernel<<<BATCH * 1024 / 256, 256, 0, stream>>>(part, s6, b6, out4m);
    gbias_kernel<<<BATCH, 256, 0, stream>>>(out4m, catv, wp1, gb);

    // head
    head_kernel<<<BN / HP, 256, 0, stream>>>(out1t, out2t, out3t, gb,
                                             wp1, sp1, bp1, wp2, sp2, bp2, wp3, sp3, bp3,
                                             wp4, (float*)d_out);
}